// Round 2
// 1068.174 us; speedup vs baseline: 1.3177x; 1.3177x over previous
//
#include <hip/hip_runtime.h>
#include <hip/hip_bf16.h>

// PCA layer: B=16, N=65536 (256x256), C=64, K=32.
// LAPACK ssyevd replication (ssytd2 + sstedc D&C + back-transform) in fp64 so
// eigenvector SIGNS match the numpy/LAPACK reference.
// R2: eigh split into 4 kernels; matrix in LDS; reflectors via uniform global loads.
// R3: merge kernels widened to 256 threads; 4 lanes cooperate per column/root.
// R4 FIX: the slaed2 deflation scan mutates shared state (zz/dloc/tl/Z) mid-scan.
//     Redundant execution across 4 non-lockstep waves raced (R3 absmax=8 failure).
//     Scan now runs on WAVE 0 ONLY (per-lane redundant scalar writes are
//     self-consistent within one wave; Z rotation is row-per-lane), K/nd
//     published via LDS, then the barrier-separated 4-lane phases proceed.

__device__ __forceinline__ double fsign(double a, double b){ return (b >= 0.0) ? fabs(a) : -fabs(a); }
__device__ __forceinline__ double slapy2(double x, double y){ return sqrt(x*x + y*y); }

__device__ __forceinline__ void slartg(double f, double g, double& cs, double& sn, double& r){
  if (g == 0.0){ cs = 1.0; sn = 0.0; r = f; }
  else if (f == 0.0){ cs = 0.0; sn = fsign(1.0, g); r = fabs(g); }
  else {
    double d = sqrt(f*f + g*g);
    cs = fabs(f)/d;
    r  = fsign(d, f);
    sn = g/r;
  }
}

__device__ __forceinline__ void slaev2(double a, double b, double c,
                                       double& rt1, double& rt2, double& cs1, double& sn1){
  double sm = a + c, df = a - c, adf = fabs(df), tb = b + b, ab = fabs(tb);
  double acmx, acmn, rt, cs, ct, acs, tn; int sgn1, sgn2;
  if (fabs(a) > fabs(c)) { acmx = a; acmn = c; } else { acmx = c; acmn = a; }
  if (adf > ab)      rt = adf*sqrt(1.0 + (ab/adf)*(ab/adf));
  else if (adf < ab) rt = ab*sqrt(1.0 + (adf/ab)*(adf/ab));
  else               rt = ab*sqrt(2.0);
  if (sm < 0.0){ rt1 = 0.5*(sm - rt); sgn1 = -1; rt2 = (acmx/rt1)*acmn - (b/rt1)*b; }
  else if (sm > 0.0){ rt1 = 0.5*(sm + rt); sgn1 = 1; rt2 = (acmx/rt1)*acmn - (b/rt1)*b; }
  else { rt1 = 0.5*rt; rt2 = -0.5*rt; sgn1 = 1; }
  if (df >= 0.0){ cs = df + rt; sgn2 = 1; } else { cs = df - rt; sgn2 = -1; }
  acs = fabs(cs);
  if (acs > ab){ ct = -tb/cs; sn1 = 1.0/sqrt(1.0 + ct*ct); cs1 = ct*sn1; }
  else {
    if (ab == 0.0){ cs1 = 1.0; sn1 = 0.0; }
    else { tn = -cs/tb; cs1 = 1.0/sqrt(1.0 + tn*tn); sn1 = tn*cs1; }
  }
  if (sgn1 == sgn2){ tn = cs1; cs1 = -sn1; sn1 = tn; }
}

__device__ __forceinline__ double wave_sum(double v){
  #pragma unroll
  for (int off = 32; off > 0; off >>= 1) v += __shfl_xor(v, off);
  return v;
}

// ---------- ssteqr('I') on a standalone 16x16 tile (ld=LDZ), faithful transcription ----------
template<int LDZ>
__device__ void steqr16(double* dd, double* ee, double* Zt, int tid,
                        double* wc, double* wsn)
{
#define DQ(i) dd[(i)-1]
#define EQ(i) ee[(i)-1]
#define ZT(r,c) Zt[(r)*LDZ+(c)]
  const int n = 16;
  const double eps = 5.9604644775390625e-8;     // slamch('E') fp32
  const double eps2 = eps*eps;
  const double safmin = 1.1754943508222875e-38; // slamch('S') fp32
  const int nmaxit = n*30;
  int jtot = 0, l1 = 1, nm1 = n-1;
  int l, lsv, lend, lendsv, m, i;
  double p, g, r, s, c, f, b2, rt1, rt2, anorm, tst;

L10:
  if (l1 > n) goto L160;
  if (l1 > 1) EQ(l1-1) = 0.0;
  if (l1 <= nm1){
    for (m = l1; m <= nm1; ++m){
      tst = fabs(EQ(m));
      if (tst == 0.0) goto L30;
      if (tst <= (sqrt(fabs(DQ(m)))*sqrt(fabs(DQ(m+1))))*eps){ EQ(m) = 0.0; goto L30; }
    }
  }
  m = n;
L30:
  l = l1; lsv = l; lend = m; lendsv = lend; l1 = m+1;
  if (lend == l) goto L10;
  anorm = 0.0;
  for (i = l; i <= lend; ++i) anorm = fmax(anorm, fabs(DQ(i)));
  for (i = l; i <  lend; ++i) anorm = fmax(anorm, fabs(EQ(i)));
  if (anorm == 0.0) goto L10;
  if (fabs(DQ(lend)) < fabs(DQ(l))){ lend = lsv; l = lendsv; }
  if (lend > l){
    // ------------------ QL iteration ------------------
L40:
    if (l != lend){
      for (m = l; m <= lend-1; ++m){
        tst = fabs(EQ(m)); tst = tst*tst;
        if (tst <= (eps2*fabs(DQ(m)))*fabs(DQ(m+1)) + safmin) goto L60;
      }
    }
    m = lend;
L60:
    if (m < lend) EQ(m) = 0.0;
    p = DQ(l);
    if (m == l) goto L80;
    if (m == l+1){
      slaev2(DQ(l), EQ(l), DQ(l+1), rt1, rt2, c, s);
      if (tid < 16){
        double t = ZT(tid, l);
        ZT(tid, l)   = c*t - s*ZT(tid, l-1);
        ZT(tid, l-1) = s*t + c*ZT(tid, l-1);
      }
      DQ(l) = rt1; DQ(l+1) = rt2; EQ(l) = 0.0;
      l += 2;
      if (l <= lend) goto L40;
      goto L140;
    }
    if (jtot == nmaxit) goto L140;
    jtot++;
    g = (DQ(l+1)-p)/(2.0*EQ(l));
    r = slapy2(g, 1.0);
    g = DQ(m) - p + (EQ(l)/(g + fsign(r, g)));
    s = 1.0; c = 1.0; p = 0.0;
    for (i = m-1; i >= l; --i){
      f = s*EQ(i); b2 = c*EQ(i);
      slartg(g, f, c, s, r);
      if (i != m-1) EQ(i+1) = r;
      g = DQ(i+1) - p;
      r = (DQ(i)-g)*s + 2.0*c*b2;
      p = s*r;
      DQ(i+1) = g + p;
      g = c*r - b2;
      wc[i] = c; wsn[i] = -s;
    }
    for (int i2 = m-1; i2 >= l; --i2){   // slasr 'R','V','B'
      double cc = wc[i2], ssv = wsn[i2];
      if (tid < 16){
        double t = ZT(tid, i2);
        ZT(tid, i2)   = cc*t - ssv*ZT(tid, i2-1);
        ZT(tid, i2-1) = ssv*t + cc*ZT(tid, i2-1);
      }
    }
    DQ(l) = DQ(l) - p;
    EQ(l) = g;
    goto L40;
L80:
    DQ(l) = p;
    l++;
    if (l <= lend) goto L40;
    goto L140;
  } else {
    // ------------------ QR iteration ------------------
L90:
    if (l != lend){
      for (m = l; m >= lend+1; --m){
        tst = fabs(EQ(m-1)); tst = tst*tst;
        if (tst <= (eps2*fabs(DQ(m)))*fabs(DQ(m-1)) + safmin) goto L110;
      }
    }
    m = lend;
L110:
    if (m > lend) EQ(m-1) = 0.0;
    p = DQ(l);
    if (m == l) goto L130;
    if (m == l-1){
      slaev2(DQ(l-1), EQ(l-1), DQ(l), rt1, rt2, c, s);
      if (tid < 16){
        double t = ZT(tid, l-1);
        ZT(tid, l-1) = c*t - s*ZT(tid, l-2);
        ZT(tid, l-2) = s*t + c*ZT(tid, l-2);
      }
      DQ(l-1) = rt1; DQ(l) = rt2; EQ(l-1) = 0.0;
      l -= 2;
      if (l >= lend) goto L90;
      goto L140;
    }
    if (jtot == nmaxit) goto L140;
    jtot++;
    g = (DQ(l-1)-p)/(2.0*EQ(l-1));
    r = slapy2(g, 1.0);
    g = DQ(m) - p + (EQ(l-1)/(g + fsign(r, g)));
    s = 1.0; c = 1.0; p = 0.0;
    for (i = m; i <= l-1; ++i){
      f = s*EQ(i); b2 = c*EQ(i);
      slartg(g, f, c, s, r);
      if (i != m) EQ(i-1) = r;
      g = DQ(i) - p;
      r = (DQ(i+1)-g)*s + 2.0*c*b2;
      p = s*r;
      DQ(i) = g + p;
      g = c*r - b2;
      wc[i] = c; wsn[i] = s;
    }
    for (int i2 = m; i2 <= l-1; ++i2){   // slasr 'R','V','F'
      double cc = wc[i2], ssv = wsn[i2];
      if (tid < 16){
        double t = ZT(tid, i2);
        ZT(tid, i2)   = cc*t - ssv*ZT(tid, i2-1);
        ZT(tid, i2-1) = ssv*t + cc*ZT(tid, i2-1);
      }
    }
    DQ(l) = DQ(l) - p;
    EQ(l-1) = g;
    goto L90;
L130:
    DQ(l) = p;
    l--;
    if (l >= lend) goto L90;
    goto L140;
  }
L140:
  if (jtot < nmaxit) goto L10;
L160:
  // selection sort ascending with column swaps (as in ssteqr)
  for (int ii = 2; ii <= n; ++ii){
    int i3 = ii-1, k2 = i3;
    p = DQ(i3);
    for (int j = ii; j <= n; ++j) if (DQ(j) < p){ k2 = j; p = DQ(j); }
    if (k2 != i3){
      DQ(k2) = DQ(i3); DQ(i3) = p;
      if (tid < 16){
        double t = ZT(tid, i3-1);
        ZT(tid, i3-1) = ZT(tid, k2-1);
        ZT(tid, k2-1) = t;
      }
    }
  }
#undef DQ
#undef EQ
#undef ZT
}

// ---------- slaed1/slaed2/slaed3 merge on a standalone NMxNM tile ----------
// Requires blockDim.x == 256. Deflation scan: wave 0 only (see R4 note at top).
// All other phases: 4 lanes (part = tid&3) cooperate per column/root j4 = tid>>2;
// strided rows r = part+4*rr are bank-conflict-free; 4-lane shuffle reductions are
// bit-identical across the group (commutative fp adds) so branches stay uniform.
template<int N1, int LD>
__device__ void merge_dc(double* Z, double* dloc, double rho_in, int tid,
                         double* zz, double* dl, double* ww, double* mu, double* wt,
                         int* idxm, int* sv, int* tl, int* fperm)
{
  const int NM = 2*N1;
  const int Q  = NM/4;                 // rows / secular terms per lane
  const double eps32 = 5.9604644775390625e-8;
  const int j4 = tid >> 2, part = tid & 3;
  __shared__ int s_kn[2];

  // z-vector: last row of Q1, first row of Q2
  if (tid < N1)       zz[tid] = Z[(N1-1)*LD + tid];
  else if (tid < NM)  zz[tid] = Z[N1*LD + tid];
  __syncthreads();
  if (rho_in < 0.0 && tid >= N1 && tid < NM) zz[tid] = -zz[tid];
  __syncthreads();
  if (tid < NM) zz[tid] *= 0.70710678118654752440;
  __syncthreads();
  double rho = fabs(2.0*rho_in);

  // merged ascending order (both halves already ascending), ties -> first half.
  // Redundant on every thread; each thread later reads only entries it wrote
  // itself (per-lane LDS program order), cross-wave writes are same-value.
  {
    int i1 = 0, i2 = 0, t = 0;
    while (i1 < N1 && i2 < N1){
      if (dloc[i1] <= dloc[N1+i2]) idxm[t++] = i1++;
      else                         idxm[t++] = N1 + (i2++);
    }
    while (i1 < N1) idxm[t++] = i1++;
    while (i2 < N1) idxm[t++] = N1 + (i2++);
  }
  double dmax = 0.0, zmax = 0.0;
  for (int i = 0; i < NM; ++i){ dmax = fmax(dmax, fabs(dloc[i])); zmax = fmax(zmax, fabs(zz[i])); }
  double tol = 8.0*eps32*fmax(dmax, zmax);

  if (rho*zmax <= tol){
    // everything deflates: just sort ascending
    double colr[Q]; double dnj = 0.0;
    if (j4 < NM){
      int s0 = idxm[j4];
      dnj = dloc[s0];
      #pragma unroll
      for (int rr = 0; rr < Q; ++rr) colr[rr] = Z[(part+4*rr)*LD + s0];
    }
    __syncthreads();
    if (j4 < NM){
      #pragma unroll
      for (int rr = 0; rr < Q; ++rr) Z[(part+4*rr)*LD + j4] = colr[rr];
      if (part == 0) dloc[j4] = dnj;
    }
    __syncthreads();
    return;
  }

  // ---- slaed2 deflation scan: WAVE 0 ONLY (mutates zz/dloc/tl/Z mid-scan;
  //      cross-wave redundant execution races — R3 bug). Within one wave each
  //      lane redundantly performs the scalar writes itself (self-consistent by
  //      per-lane LDS program order); the Z rotation is strictly row-per-lane.
  int K, nd;
  if (tid < 64){
    K = 0; nd = 0;
    int have = 0, pj = 0;
    for (int t = 0; t < NM; ++t){
      int nj = idxm[t];
      if (rho*fabs(zz[nj]) <= tol){
        for (int q = nd; q > 0; --q) tl[q] = tl[q-1];
        tl[0] = nj; nd++;
        continue;
      }
      if (!have){ pj = nj; have = 1; continue; }
      {
        double sZ = zz[pj], cZ = zz[nj];
        double tau2 = slapy2(cZ, sZ);
        double tgap = dloc[nj] - dloc[pj];
        cZ /= tau2; sZ = -sZ/tau2;
        if (fabs(tgap*cZ*sZ) <= tol){
          zz[nj] = tau2; zz[pj] = 0.0;
          if (tid < NM){
            double xq = Z[tid*LD + pj], yq = Z[tid*LD + nj];
            Z[tid*LD + pj] = cZ*xq + sZ*yq;
            Z[tid*LD + nj] = cZ*yq - sZ*xq;
          }
          double t2 = dloc[pj]*cZ*cZ + dloc[nj]*sZ*sZ;
          double t3 = dloc[pj]*sZ*sZ + dloc[nj]*cZ*cZ;
          dloc[nj] = t3; dloc[pj] = t2;
          for (int q = nd; q > 0; --q) tl[q] = tl[q-1];
          tl[0] = pj; nd++;
          { int q = 0;
            while (q+1 < nd && dloc[tl[q]] < dloc[tl[q+1]]){
              int tt = tl[q]; tl[q] = tl[q+1]; tl[q+1] = tt; q++;
            } }
          pj = nj;
        } else {
          sv[K] = pj; dl[K] = dloc[pj]; ww[K] = zz[pj]; K++;
          pj = nj;
        }
      }
    }
    sv[K] = pj; dl[K] = dloc[pj]; ww[K] = zz[pj]; K++;
    if (tid == 0){ s_kn[0] = K; s_kn[1] = nd; }
  }
  __syncthreads();
  K = s_kn[0]; nd = s_kn[1];

  // ---- secular equation roots: 4-lane group per root j4 ----
  if (j4 < K){
    double dj = dl[j4];
    // register-cache this lane's terms; pad with inert entries so the inner
    // loops fully unroll (independent fp64 divides pipeline instead of chaining)
    double dlr[Q], wr[Q];
    double zs2p = 0.0;
    #pragma unroll
    for (int t = 0; t < Q; ++t){
      int i = part + 4*t;
      if (i < K){ double wv = ww[i]; dlr[t] = dl[i]; wr[t] = rho*wv*wv; zs2p += wv*wv; }
      else      { dlr[t] = 1.0e300; wr[t] = 0.0; }
    }
    zs2p += __shfl_xor(zs2p, 1); zs2p += __shfl_xor(zs2p, 2);
    double lo = 0.0, hi = (j4 < K-1) ? (dl[j4+1]-dj) : rho*zs2p;
    for (int it = 0; it < 24; ++it){
      double mid = 0.5*(lo+hi);
      if (mid == lo || mid == hi) break;
      double fvp = 0.0;
      #pragma unroll
      for (int t = 0; t < Q; ++t) fvp += wr[t]/((dlr[t]-dj) - mid);
      fvp += __shfl_xor(fvp, 1); fvp += __shfl_xor(fvp, 2);
      double fv = 1.0 + fvp;
      if (fv < 0.0) lo = mid; else hi = mid;
    }
    double muv = 0.5*(lo+hi);
    for (int it = 0; it < 14; ++it){
      double fvp = 0.0, fpp = 0.0;
      #pragma unroll
      for (int t = 0; t < Q; ++t){
        double den = (dlr[t]-dj) - muv;
        double inv = 1.0/den;
        double tq = wr[t]*inv;
        fvp += tq; fpp += tq*inv;
      }
      fvp += __shfl_xor(fvp, 1); fvp += __shfl_xor(fvp, 2);
      fpp += __shfl_xor(fpp, 1); fpp += __shfl_xor(fpp, 2);
      double fv = 1.0 + fvp;
      if (fv == 0.0) break;
      if (fv < 0.0) lo = muv; else hi = muv;
      double mn = muv - fv/fpp;
      if (!(mn > lo && mn < hi)) mn = 0.5*(lo+hi);
      if (mn == muv) break;
      muv = mn;
    }
    if (part == 0) mu[j4] = muv;
  }
  __syncthreads();

  // ---- Gu z-tilde (slaed3 sign convention), 4-way product split ----
  if (j4 < K){
    double dj = dl[j4];
    double pp = 1.0;
    for (int i2 = part; i2 < K; i2 += 4){
      if (i2 == j4) continue;
      double dij = dj - dl[i2];
      pp *= (dij - mu[i2])/dij;
    }
    pp *= __shfl_xor(pp, 1); pp *= __shfl_xor(pp, 2);
    double prod = -mu[j4]*pp;
    if (part == 0) wt[j4] = fsign(sqrt(fmax(-prod, 0.0)), ww[j4]);
  }
  __syncthreads();

  // ---- final permutation: slamrg(K asc, nd tail traversed backward) ----
  // Redundant-uniform: reads only barrier-stable data, writes same values.
  {
    int a = 0, q = nd-1, t = 0;
    while (a < K && q >= 0){
      if (dl[a]+mu[a] <= dloc[tl[q]]) { fperm[t++] = a; a++; }
      else { fperm[t++] = K+q; q--; }
    }
    while (a < K)  { fperm[t++] = a; a++; }
    while (q >= 0) { fperm[t++] = K+q; q--; }
  }
  __syncthreads();

  // ---- assemble new columns (4 lanes per final column, strided rows) ----
  double colr[Q]; double dnj = 0.0;
  if (j4 < NM){
    int src = fperm[j4];
    if (src < K){
      double muj = mu[src];
      double ds  = dl[src];
      double nrmp = 0.0;
      for (int i = part; i < K; i += 4){
        double del = (dl[i]-ds) - muj;
        double qv = wt[i]/del;
        nrmp += qv*qv;
      }
      nrmp += __shfl_xor(nrmp, 1); nrmp += __shfl_xor(nrmp, 2);
      double invn = 1.0/sqrt(nrmp);
      #pragma unroll
      for (int rr = 0; rr < Q; ++rr) colr[rr] = 0.0;
      for (int i = 0; i < K; ++i){
        double del = (dl[i]-ds) - muj;
        double sval = (wt[i]/del)*invn;
        int cq = sv[i];
        #pragma unroll
        for (int rr = 0; rr < Q; ++rr) colr[rr] += Z[(part+4*rr)*LD + cq]*sval;
      }
      dnj = ds + muj;
    } else {
      int tq2 = tl[src-K];
      #pragma unroll
      for (int rr = 0; rr < Q; ++rr) colr[rr] = Z[(part+4*rr)*LD + tq2];
      dnj = dloc[tq2];
    }
  }
  __syncthreads();
  if (j4 < NM){
    #pragma unroll
    for (int rr = 0; rr < Q; ++rr) Z[(part+4*rr)*LD + j4] = colr[rr];
    if (part == 0) dloc[j4] = dnj;
  }
  __syncthreads();
}

// ---------------- Phase A: Gram + channel sums ----------------
__global__ __launch_bounds__(256) void cov_kernel(const float* __restrict__ x,
                                                  double* __restrict__ gram,
                                                  double* __restrict__ chsum)
{
  __shared__ __align__(16) float tile[16][64];
  const int b   = blockIdx.x >> 5;
  const int ch  = blockIdx.x & 31;
  const int tid = threadIdx.x;
  const int ti = tid >> 4, tj = tid & 15;
  const int lrow = tid >> 4, lf4 = tid & 15;
  const int cch = tid & 63, crr = tid >> 6;
  float acc[4][4];
  #pragma unroll
  for (int a = 0; a < 4; ++a)
    #pragma unroll
    for (int c = 0; c < 4; ++c) acc[a][c] = 0.f;
  float csum = 0.f;
  const int rbase = ch*2048;
  for (int r0 = 0; r0 < 2048; r0 += 16){
    const float4 v = *(const float4*)(x + (((size_t)b*65536 + rbase + r0 + lrow)*64 + lf4*4));
    __syncthreads();
    *(float4*)&tile[lrow][lf4*4] = v;
    __syncthreads();
    #pragma unroll
    for (int rr = 0; rr < 16; ++rr){
      float4 xi = *(const float4*)&tile[rr][4*ti];
      float4 xj = *(const float4*)&tile[rr][4*tj];
      acc[0][0] += xi.x*xj.x; acc[0][1] += xi.x*xj.y; acc[0][2] += xi.x*xj.z; acc[0][3] += xi.x*xj.w;
      acc[1][0] += xi.y*xj.x; acc[1][1] += xi.y*xj.y; acc[1][2] += xi.y*xj.z; acc[1][3] += xi.y*xj.w;
      acc[2][0] += xi.z*xj.x; acc[2][1] += xi.z*xj.y; acc[2][2] += xi.z*xj.z; acc[2][3] += xi.z*xj.w;
      acc[3][0] += xi.w*xj.x; acc[3][1] += xi.w*xj.y; acc[3][2] += xi.w*xj.z; acc[3][3] += xi.w*xj.w;
    }
    #pragma unroll
    for (int rr2 = 0; rr2 < 4; ++rr2) csum += tile[crr + rr2*4][cch];
  }
  double* gb = gram + (size_t)b*4096;
  #pragma unroll
  for (int a = 0; a < 4; ++a)
    #pragma unroll
    for (int c = 0; c < 4; ++c)
      atomicAdd(&gb[(4*ti+a)*64 + (4*tj+c)], (double)acc[a][c]);
  atomicAdd(&chsum[b*64 + cch], (double)csum);
}

// ---------------- Phase B1: ssytd2 (dense symmetric trailing update in LDS) ----------------
__global__ __launch_bounds__(64) void tridiag_kernel(const double* __restrict__ gram,
                                                     const double* __restrict__ chsum,
                                                     double* __restrict__ dG,
                                                     double* __restrict__ eG,
                                                     double* __restrict__ tauG,
                                                     double* __restrict__ VlG,
                                                     float* __restrict__ meanG)
{
  __shared__ double As[64*65];
  __shared__ double vv_[64], wv_[64], mu_s[64], es_s[64], tau_s[64];
  const int b = blockIdx.x;
  const int tid = threadIdx.x;
  const double* gb = gram + (size_t)b*4096;

  double mval = chsum[b*64+tid]*(1.0/65536.0);
  meanG[b*64+tid] = (float)mval;
  mu_s[tid] = mval;
  __syncthreads();
  for (int idx = tid; idx < 4096; idx += 64){
    int i = idx >> 6, j = idx & 63;
    As[i*65+j] = (gb[idx] - 65536.0*mu_s[i]*mu_s[j])*(1.0/65535.0);
  }
  __syncthreads();

  for (int i = 0; i < 63; ++i){
    double alpha = As[(i+1)*65+i];
    double xv0 = (tid >= i+2) ? As[tid*65+i] : 0.0;
    double xn2 = wave_sum(xv0*xv0);
    if (xn2 == 0.0){
      es_s[i] = alpha; tau_s[i] = 0.0;
      VlG[((size_t)b*63 + i)*64 + tid] = 0.0;
      __syncthreads();
      continue;
    }
    double xnorm = sqrt(xn2);
    double betav = -fsign(slapy2(alpha, xnorm), alpha);
    double taui  = (betav-alpha)/betav;
    double invs  = 1.0/(alpha-betav);
    double vval = (tid == i+1) ? 1.0 : ((tid >= i+2) ? xv0*invs : 0.0);
    vv_[tid] = vval;
    VlG[((size_t)b*63 + i)*64 + tid] = vval;   // coalesced reflector store (transposed layout)
    __syncthreads();
    double xvr = 0.0;
    if (tid >= i+1){
      for (int c2 = i+1; c2 < 64; ++c2) xvr += As[tid*65+c2]*vv_[c2];
      xvr *= taui;
    }
    double dot = wave_sum((tid >= i+1) ? xvr*vval : 0.0);
    double alf = -0.5*taui*dot;
    wv_[tid] = (tid >= i+1) ? (xvr + alf*vval) : 0.0;
    __syncthreads();
    if (tid >= i+1){
      double vr = vval, wr = wv_[tid];
      for (int c2 = i+1; c2 < 64; ++c2) As[tid*65+c2] -= vr*wv_[c2] + wr*vv_[c2];
    }
    es_s[i] = betav; tau_s[i] = taui;
    __syncthreads();
  }
  dG[b*64+tid]   = As[tid*65+tid];
  eG[b*64+tid]   = (tid < 63) ? es_s[tid]  : 0.0;
  tauG[b*64+tid] = (tid < 63) ? tau_s[tid] : 0.0;
}

// ---------------- Phase B2: 64 independent 16x16 steqr ----------------
__global__ __launch_bounds__(64) void steqr_kernel(double* __restrict__ dG,
                                                   const double* __restrict__ eG,
                                                   double* __restrict__ Zg)
{
  __shared__ double Zt[16*17];
  __shared__ double dd[16], ee[16], wc[20], wsn[20];
  const int b = blockIdx.x >> 2, s = blockIdx.x & 3;
  const int tid = threadIdx.x;

  // load tridiag segment + D&C rank-one cut adjustments
  {
    double dv = (tid < 16) ? dG[b*64 + 16*s + tid] : 0.0;
    if (tid == 0  && s > 0) dv -= fabs(eG[b*64 + 16*s - 1]);
    if (tid == 15 && s < 3) dv -= fabs(eG[b*64 + 16*s + 15]);
    if (tid < 16) dd[tid] = dv;
    if (tid < 15) ee[tid] = eG[b*64 + 16*s + tid];
    if (tid == 15) ee[15] = 0.0;
  }
  for (int idx = tid; idx < 16*17; idx += 64) Zt[idx] = 0.0;
  __syncthreads();
  if (tid < 16) Zt[tid*17+tid] = 1.0;
  __syncthreads();

  steqr16<17>(dd, ee, Zt, tid, wc, wsn);
  __syncthreads();

  // store compact 16x16 block + updated d
  for (int idx = tid; idx < 256; idx += 64){
    int r = idx >> 4, c = idx & 15;
    Zg[(size_t)b*4096 + s*256 + idx] = Zt[r*17+c];
  }
  if (tid < 16) dG[b*64 + 16*s + tid] = dd[tid];
}

// ---------------- Phase B3: two independent 16+16 merges (256 thr) ----------------
__global__ __launch_bounds__(256) void merge16_kernel(double* __restrict__ Zg,
                                                      double* __restrict__ dG,
                                                      const double* __restrict__ eG)
{
  __shared__ double Z32[32*33];
  __shared__ double dloc[32];
  __shared__ double zz[32], dl[32], ww[32], mu[32], wt[32];
  __shared__ int idxm[32], sv[32], tl[32], fp[32];
  const int b = blockIdx.x >> 1, h = blockIdx.x & 1;
  const int tid = threadIdx.x;

  for (int idx = tid; idx < 32*33; idx += 256) Z32[idx] = 0.0;
  if (tid < 32) dloc[tid] = dG[b*64 + 32*h + tid];
  __syncthreads();
  {
    int idx = tid;  // exactly 256 elements per 16x16 block
    int r = idx >> 4, c = idx & 15;
    Z32[r*33 + c]           = Zg[(size_t)b*4096 + (2*h)*256   + idx];
    Z32[(16+r)*33 + (16+c)] = Zg[(size_t)b*4096 + (2*h+1)*256 + idx];
  }
  __syncthreads();

  double rho_in = eG[b*64 + 32*h + 15];
  merge_dc<16,33>(Z32, dloc, rho_in, tid, zz, dl, ww, mu, wt, idxm, sv, tl, fp);

  // store 32x32 result to the upper half of Zg[b] (disjoint from the inputs)
  for (int idx = tid; idx < 1024; idx += 256){
    int r = idx >> 5, c = idx & 31;
    Zg[(size_t)b*4096 + 2048 + h*1024 + idx] = Z32[r*33 + c];
  }
  if (tid < 32) dG[b*64 + 32*h + tid] = dloc[tid];
}

// ---------------- Phase B4: 32+32 merge + back-transform + output V (256 thr) ----------------
__global__ __launch_bounds__(256) void merge32_bt_kernel(const double* __restrict__ Zg,
                                                         double* __restrict__ dG,
                                                         const double* __restrict__ eG,
                                                         const double* __restrict__ tauG,
                                                         const double* __restrict__ VlG,
                                                         float* __restrict__ Vt)
{
  __shared__ double Z64[64*65];
  __shared__ double Vl_s[63*64];
  __shared__ double dloc[64], tau_l[64];
  __shared__ double zz[64], dl[64], ww[64], mu[64], wt[64];
  __shared__ int idxm[64], sv[64], tl[64], fp[64];
  const int b = blockIdx.x;
  const int tid = threadIdx.x;

  for (int idx = tid; idx < 64*65; idx += 256) Z64[idx] = 0.0;
  if (tid < 64){ dloc[tid] = dG[b*64 + tid]; tau_l[tid] = tauG[b*64 + tid]; }
  // stage all reflectors once (kills per-step uniform global-load latency chains)
  for (int idx = tid; idx < 63*64; idx += 256) Vl_s[idx] = VlG[(size_t)b*63*64 + idx];
  __syncthreads();
  for (int idx = tid; idx < 1024; idx += 256){
    int r = idx >> 5, c = idx & 31;
    Z64[r*65 + c]           = Zg[(size_t)b*4096 + 2048 + idx];
    Z64[(32+r)*65 + (32+c)] = Zg[(size_t)b*4096 + 3072 + idx];
  }
  __syncthreads();

  double rho_in = eG[b*64 + 31];
  merge_dc<32,65>(Z64, dloc, rho_in, tid, zz, dl, ww, mu, wt, idxm, sv, tl, fp);

  // back-transform: Z := H1...H63 * Z, entirely in registers.
  // Lane (jc = tid>>2, part = tid&3) owns rows {part+4*rr} of column jc.
  // Vl rows are zero for r <= i and 1 at r == i+1, so the unguarded FMA form
  // reproduces the original guarded loops exactly.
  {
    const int jc = tid >> 2, part = tid & 3;
    double z[16];
    #pragma unroll
    for (int rr = 0; rr < 16; ++rr) z[rr] = Z64[(part + 4*rr)*65 + jc];
    for (int i = 62; i >= 0; --i){
      double taui = tau_l[i];
      if (taui == 0.0) continue;
      double vir[16];
      #pragma unroll
      for (int rr = 0; rr < 16; ++rr) vir[rr] = Vl_s[i*64 + part + 4*rr];
      double w0 = 0.0, w1 = 0.0;
      #pragma unroll
      for (int rr = 0; rr < 16; rr += 2){ w0 += vir[rr]*z[rr]; w1 += vir[rr+1]*z[rr+1]; }
      double w = w0 + w1;
      w += __shfl_xor(w, 1);
      w += __shfl_xor(w, 2);
      w *= taui;
      #pragma unroll
      for (int rr = 0; rr < 16; ++rr) z[rr] -= vir[rr]*w;
    }
    // each lane reads/writes only its own (row,col) elements -> no barrier needed
    #pragma unroll
    for (int rr = 0; rr < 16; ++rr) Z64[(part + 4*rr)*65 + jc] = z[rr];
  }
  __syncthreads();

  // Vt[b][c][k] = V[c][63-k]  (descending top-32)
  for (int idx = tid; idx < 2048; idx += 256){
    int c2 = idx >> 5, k = idx & 31;
    Vt[(size_t)b*2048 + idx] = (float)Z64[c2*65 + (63-k)];
  }
}

// ---------------- Phase C: projection ----------------
__global__ __launch_bounds__(256) void proj_kernel(const float* __restrict__ x,
                                                   const float* __restrict__ Vt,
                                                   const float* __restrict__ meanf,
                                                   float* __restrict__ out)
{
  __shared__ float Vs[64][32];
  __shared__ float ms[64];
  const int b = blockIdx.x >> 8;
  const int rb = blockIdx.x & 255;
  const int tid = threadIdx.x;
  for (int idx = tid; idx < 2048; idx += 256) ((float*)Vs)[idx] = Vt[(size_t)b*2048 + idx];
  if (tid < 64) ms[tid] = meanf[b*64+tid];
  __syncthreads();
  const size_t row = (size_t)b*65536 + (size_t)rb*256 + tid;
  const float4* xr = (const float4*)(x + row*64);
  float acc[32];
  #pragma unroll
  for (int k = 0; k < 32; ++k) acc[k] = 0.f;
  #pragma unroll
  for (int c4 = 0; c4 < 16; ++c4){
    float4 xv = xr[c4];
    float t0 = xv.x - ms[4*c4+0];
    float t1 = xv.y - ms[4*c4+1];
    float t2 = xv.z - ms[4*c4+2];
    float t3 = xv.w - ms[4*c4+3];
    #pragma unroll
    for (int k = 0; k < 32; ++k) acc[k] += t0*Vs[4*c4+0][k];
    #pragma unroll
    for (int k = 0; k < 32; ++k) acc[k] += t1*Vs[4*c4+1][k];
    #pragma unroll
    for (int k = 0; k < 32; ++k) acc[k] += t2*Vs[4*c4+2][k];
    #pragma unroll
    for (int k = 0; k < 32; ++k) acc[k] += t3*Vs[4*c4+3][k];
  }
  float4* op = (float4*)(out + row*32);
  #pragma unroll
  for (int k4 = 0; k4 < 8; ++k4)
    op[k4] = make_float4(acc[4*k4], acc[4*k4+1], acc[4*k4+2], acc[4*k4+3]);
}

extern "C" void kernel_launch(void* const* d_in, const int* in_sizes, int n_in,
                              void* d_out, int out_size, void* d_ws, size_t ws_size,
                              hipStream_t stream)
{
  const float* x = (const float*)d_in[0];
  float* out = (float*)d_out;
  char* ws = (char*)d_ws;
  // ws layout (bytes):
  //   [0,       524288) gram 16x64x64 dbl (atomics; zeroed) -> reused as Zg after tridiag
  //   [524288,  532480) chsum 16x64 dbl (atomics; zeroed)
  //   [532480,  540672) dG   16x64 dbl
  //   [540672,  548864) eG   16x64 dbl
  //   [548864,  557056) tauG 16x64 dbl
  //   [557056, 1073152) VlG  16x63x64 dbl (reflectors, transposed: Vl[b][i][r])
  //   [1073152,1204224) Vt   16x64x32 f32
  //   [1204224,1208320) mean 16x64 f32
  double* gram  = (double*)(ws);
  double* Zg    = (double*)(ws);             // alias: gram dead after tridiag_kernel
  double* chsum = (double*)(ws + 524288);
  double* dG    = (double*)(ws + 532480);
  double* eG    = (double*)(ws + 540672);
  double* tauG  = (double*)(ws + 548864);
  double* VlG   = (double*)(ws + 557056);
  float*  Vt    = (float*) (ws + 1073152);
  float*  mf    = (float*) (ws + 1204224);

  hipMemsetAsync(ws, 0, 532480, stream);
  cov_kernel     <<<dim3(512),  dim3(256), 0, stream>>>(x, gram, chsum);
  tridiag_kernel <<<dim3(16),   dim3(64),  0, stream>>>(gram, chsum, dG, eG, tauG, VlG, mf);
  steqr_kernel   <<<dim3(64),   dim3(64),  0, stream>>>(dG, eG, Zg);
  merge16_kernel <<<dim3(32),   dim3(256), 0, stream>>>(Zg, dG, eG);
  merge32_bt_kernel<<<dim3(16), dim3(256), 0, stream>>>(Zg, dG, eG, tauG, VlG, Vt);
  proj_kernel    <<<dim3(4096), dim3(256), 0, stream>>>(x, Vt, mf, out);
}

// Round 3
// 1034.332 us; speedup vs baseline: 1.3608x; 1.0327x over previous
//
#include <hip/hip_runtime.h>
#include <hip/hip_bf16.h>

// PCA layer: B=16, N=65536 (256x256), C=64, K=32.
// LAPACK ssyevd replication (ssytd2 + sstedc D&C + back-transform) in fp64 so
// eigenvector SIGNS match the numpy/LAPACK reference.
// R2: eigh split into 4 kernels; matrix in LDS; reflectors via uniform global loads.
// R3: merge kernels widened to 256 threads; 4 lanes cooperate per column/root.
// R4 FIX: slaed2 deflation scan runs on wave 0 only (cross-wave redundant
//     execution raced at 256 threads).
// R5: cov_kernel: 32-row tiles + register prefetch (load tile k+1 during compute
//     of tile k) — the old sync load->barrier->compute loop left HBM latency
//     un-hidden at 2 blocks/CU. tridiag_kernel: guarded partial-range inner loops
//     (runtime lower bound => no unroll => serial lgkmcnt-bound LDS chains)
//     replaced by FULL-range unrolled loops; vv_/wv_ are exactly 0 outside the
//     active range so results are identical, but reads now pipeline. proj_kernel:
//     Vs read as float4 (512 b128 broadcast reads instead of 2048 b32).

__device__ __forceinline__ double fsign(double a, double b){ return (b >= 0.0) ? fabs(a) : -fabs(a); }
__device__ __forceinline__ double slapy2(double x, double y){ return sqrt(x*x + y*y); }

__device__ __forceinline__ void slartg(double f, double g, double& cs, double& sn, double& r){
  if (g == 0.0){ cs = 1.0; sn = 0.0; r = f; }
  else if (f == 0.0){ cs = 0.0; sn = fsign(1.0, g); r = fabs(g); }
  else {
    double d = sqrt(f*f + g*g);
    cs = fabs(f)/d;
    r  = fsign(d, f);
    sn = g/r;
  }
}

__device__ __forceinline__ void slaev2(double a, double b, double c,
                                       double& rt1, double& rt2, double& cs1, double& sn1){
  double sm = a + c, df = a - c, adf = fabs(df), tb = b + b, ab = fabs(tb);
  double acmx, acmn, rt, cs, ct, acs, tn; int sgn1, sgn2;
  if (fabs(a) > fabs(c)) { acmx = a; acmn = c; } else { acmx = c; acmn = a; }
  if (adf > ab)      rt = adf*sqrt(1.0 + (ab/adf)*(ab/adf));
  else if (adf < ab) rt = ab*sqrt(1.0 + (adf/ab)*(adf/ab));
  else               rt = ab*sqrt(2.0);
  if (sm < 0.0){ rt1 = 0.5*(sm - rt); sgn1 = -1; rt2 = (acmx/rt1)*acmn - (b/rt1)*b; }
  else if (sm > 0.0){ rt1 = 0.5*(sm + rt); sgn1 = 1; rt2 = (acmx/rt1)*acmn - (b/rt1)*b; }
  else { rt1 = 0.5*rt; rt2 = -0.5*rt; sgn1 = 1; }
  if (df >= 0.0){ cs = df + rt; sgn2 = 1; } else { cs = df - rt; sgn2 = -1; }
  acs = fabs(cs);
  if (acs > ab){ ct = -tb/cs; sn1 = 1.0/sqrt(1.0 + ct*ct); cs1 = ct*sn1; }
  else {
    if (ab == 0.0){ cs1 = 1.0; sn1 = 0.0; }
    else { tn = -cs/tb; cs1 = 1.0/sqrt(1.0 + tn*tn); sn1 = tn*cs1; }
  }
  if (sgn1 == sgn2){ tn = cs1; cs1 = -sn1; sn1 = tn; }
}

__device__ __forceinline__ double wave_sum(double v){
  #pragma unroll
  for (int off = 32; off > 0; off >>= 1) v += __shfl_xor(v, off);
  return v;
}

// ---------- ssteqr('I') on a standalone 16x16 tile (ld=LDZ), faithful transcription ----------
template<int LDZ>
__device__ void steqr16(double* dd, double* ee, double* Zt, int tid,
                        double* wc, double* wsn)
{
#define DQ(i) dd[(i)-1]
#define EQ(i) ee[(i)-1]
#define ZT(r,c) Zt[(r)*LDZ+(c)]
  const int n = 16;
  const double eps = 5.9604644775390625e-8;     // slamch('E') fp32
  const double eps2 = eps*eps;
  const double safmin = 1.1754943508222875e-38; // slamch('S') fp32
  const int nmaxit = n*30;
  int jtot = 0, l1 = 1, nm1 = n-1;
  int l, lsv, lend, lendsv, m, i;
  double p, g, r, s, c, f, b2, rt1, rt2, anorm, tst;

L10:
  if (l1 > n) goto L160;
  if (l1 > 1) EQ(l1-1) = 0.0;
  if (l1 <= nm1){
    for (m = l1; m <= nm1; ++m){
      tst = fabs(EQ(m));
      if (tst == 0.0) goto L30;
      if (tst <= (sqrt(fabs(DQ(m)))*sqrt(fabs(DQ(m+1))))*eps){ EQ(m) = 0.0; goto L30; }
    }
  }
  m = n;
L30:
  l = l1; lsv = l; lend = m; lendsv = lend; l1 = m+1;
  if (lend == l) goto L10;
  anorm = 0.0;
  for (i = l; i <= lend; ++i) anorm = fmax(anorm, fabs(DQ(i)));
  for (i = l; i <  lend; ++i) anorm = fmax(anorm, fabs(EQ(i)));
  if (anorm == 0.0) goto L10;
  if (fabs(DQ(lend)) < fabs(DQ(l))){ lend = lsv; l = lendsv; }
  if (lend > l){
    // ------------------ QL iteration ------------------
L40:
    if (l != lend){
      for (m = l; m <= lend-1; ++m){
        tst = fabs(EQ(m)); tst = tst*tst;
        if (tst <= (eps2*fabs(DQ(m)))*fabs(DQ(m+1)) + safmin) goto L60;
      }
    }
    m = lend;
L60:
    if (m < lend) EQ(m) = 0.0;
    p = DQ(l);
    if (m == l) goto L80;
    if (m == l+1){
      slaev2(DQ(l), EQ(l), DQ(l+1), rt1, rt2, c, s);
      if (tid < 16){
        double t = ZT(tid, l);
        ZT(tid, l)   = c*t - s*ZT(tid, l-1);
        ZT(tid, l-1) = s*t + c*ZT(tid, l-1);
      }
      DQ(l) = rt1; DQ(l+1) = rt2; EQ(l) = 0.0;
      l += 2;
      if (l <= lend) goto L40;
      goto L140;
    }
    if (jtot == nmaxit) goto L140;
    jtot++;
    g = (DQ(l+1)-p)/(2.0*EQ(l));
    r = slapy2(g, 1.0);
    g = DQ(m) - p + (EQ(l)/(g + fsign(r, g)));
    s = 1.0; c = 1.0; p = 0.0;
    for (i = m-1; i >= l; --i){
      f = s*EQ(i); b2 = c*EQ(i);
      slartg(g, f, c, s, r);
      if (i != m-1) EQ(i+1) = r;
      g = DQ(i+1) - p;
      r = (DQ(i)-g)*s + 2.0*c*b2;
      p = s*r;
      DQ(i+1) = g + p;
      g = c*r - b2;
      wc[i] = c; wsn[i] = -s;
    }
    for (int i2 = m-1; i2 >= l; --i2){   // slasr 'R','V','B'
      double cc = wc[i2], ssv = wsn[i2];
      if (tid < 16){
        double t = ZT(tid, i2);
        ZT(tid, i2)   = cc*t - ssv*ZT(tid, i2-1);
        ZT(tid, i2-1) = ssv*t + cc*ZT(tid, i2-1);
      }
    }
    DQ(l) = DQ(l) - p;
    EQ(l) = g;
    goto L40;
L80:
    DQ(l) = p;
    l++;
    if (l <= lend) goto L40;
    goto L140;
  } else {
    // ------------------ QR iteration ------------------
L90:
    if (l != lend){
      for (m = l; m >= lend+1; --m){
        tst = fabs(EQ(m-1)); tst = tst*tst;
        if (tst <= (eps2*fabs(DQ(m)))*fabs(DQ(m-1)) + safmin) goto L110;
      }
    }
    m = lend;
L110:
    if (m > lend) EQ(m-1) = 0.0;
    p = DQ(l);
    if (m == l) goto L130;
    if (m == l-1){
      slaev2(DQ(l-1), EQ(l-1), DQ(l), rt1, rt2, c, s);
      if (tid < 16){
        double t = ZT(tid, l-1);
        ZT(tid, l-1) = c*t - s*ZT(tid, l-2);
        ZT(tid, l-2) = s*t + c*ZT(tid, l-2);
      }
      DQ(l-1) = rt1; DQ(l) = rt2; EQ(l-1) = 0.0;
      l -= 2;
      if (l >= lend) goto L90;
      goto L140;
    }
    if (jtot == nmaxit) goto L140;
    jtot++;
    g = (DQ(l-1)-p)/(2.0*EQ(l-1));
    r = slapy2(g, 1.0);
    g = DQ(m) - p + (EQ(l-1)/(g + fsign(r, g)));
    s = 1.0; c = 1.0; p = 0.0;
    for (i = m; i <= l-1; ++i){
      f = s*EQ(i); b2 = c*EQ(i);
      slartg(g, f, c, s, r);
      if (i != m) EQ(i-1) = r;
      g = DQ(i) - p;
      r = (DQ(i+1)-g)*s + 2.0*c*b2;
      p = s*r;
      DQ(i) = g + p;
      g = c*r - b2;
      wc[i] = c; wsn[i] = s;
    }
    for (int i2 = m; i2 <= l-1; ++i2){   // slasr 'R','V','F'
      double cc = wc[i2], ssv = wsn[i2];
      if (tid < 16){
        double t = ZT(tid, i2);
        ZT(tid, i2)   = cc*t - ssv*ZT(tid, i2-1);
        ZT(tid, i2-1) = ssv*t + cc*ZT(tid, i2-1);
      }
    }
    DQ(l) = DQ(l) - p;
    EQ(l-1) = g;
    goto L90;
L130:
    DQ(l) = p;
    l--;
    if (l >= lend) goto L90;
    goto L140;
  }
L140:
  if (jtot < nmaxit) goto L10;
L160:
  // selection sort ascending with column swaps (as in ssteqr)
  for (int ii = 2; ii <= n; ++ii){
    int i3 = ii-1, k2 = i3;
    p = DQ(i3);
    for (int j = ii; j <= n; ++j) if (DQ(j) < p){ k2 = j; p = DQ(j); }
    if (k2 != i3){
      DQ(k2) = DQ(i3); DQ(i3) = p;
      if (tid < 16){
        double t = ZT(tid, i3-1);
        ZT(tid, i3-1) = ZT(tid, k2-1);
        ZT(tid, k2-1) = t;
      }
    }
  }
#undef DQ
#undef EQ
#undef ZT
}

// ---------- slaed1/slaed2/slaed3 merge on a standalone NMxNM tile ----------
// Requires blockDim.x == 256. Deflation scan: wave 0 only (see R4 note at top).
// All other phases: 4 lanes (part = tid&3) cooperate per column/root j4 = tid>>2;
// strided rows r = part+4*rr are bank-conflict-free; 4-lane shuffle reductions are
// bit-identical across the group (commutative fp adds) so branches stay uniform.
template<int N1, int LD>
__device__ void merge_dc(double* Z, double* dloc, double rho_in, int tid,
                         double* zz, double* dl, double* ww, double* mu, double* wt,
                         int* idxm, int* sv, int* tl, int* fperm)
{
  const int NM = 2*N1;
  const int Q  = NM/4;                 // rows / secular terms per lane
  const double eps32 = 5.9604644775390625e-8;
  const int j4 = tid >> 2, part = tid & 3;
  __shared__ int s_kn[2];

  // z-vector: last row of Q1, first row of Q2
  if (tid < N1)       zz[tid] = Z[(N1-1)*LD + tid];
  else if (tid < NM)  zz[tid] = Z[N1*LD + tid];
  __syncthreads();
  if (rho_in < 0.0 && tid >= N1 && tid < NM) zz[tid] = -zz[tid];
  __syncthreads();
  if (tid < NM) zz[tid] *= 0.70710678118654752440;
  __syncthreads();
  double rho = fabs(2.0*rho_in);

  // merged ascending order (both halves already ascending), ties -> first half.
  // Redundant on every thread; each thread later reads only entries it wrote
  // itself (per-lane LDS program order), cross-wave writes are same-value.
  {
    int i1 = 0, i2 = 0, t = 0;
    while (i1 < N1 && i2 < N1){
      if (dloc[i1] <= dloc[N1+i2]) idxm[t++] = i1++;
      else                         idxm[t++] = N1 + (i2++);
    }
    while (i1 < N1) idxm[t++] = i1++;
    while (i2 < N1) idxm[t++] = N1 + (i2++);
  }
  double dmax = 0.0, zmax = 0.0;
  for (int i = 0; i < NM; ++i){ dmax = fmax(dmax, fabs(dloc[i])); zmax = fmax(zmax, fabs(zz[i])); }
  double tol = 8.0*eps32*fmax(dmax, zmax);

  if (rho*zmax <= tol){
    // everything deflates: just sort ascending
    double colr[Q]; double dnj = 0.0;
    if (j4 < NM){
      int s0 = idxm[j4];
      dnj = dloc[s0];
      #pragma unroll
      for (int rr = 0; rr < Q; ++rr) colr[rr] = Z[(part+4*rr)*LD + s0];
    }
    __syncthreads();
    if (j4 < NM){
      #pragma unroll
      for (int rr = 0; rr < Q; ++rr) Z[(part+4*rr)*LD + j4] = colr[rr];
      if (part == 0) dloc[j4] = dnj;
    }
    __syncthreads();
    return;
  }

  // ---- slaed2 deflation scan: WAVE 0 ONLY (mutates zz/dloc/tl/Z mid-scan;
  //      cross-wave redundant execution races — R3 bug). Within one wave each
  //      lane redundantly performs the scalar writes itself (self-consistent by
  //      per-lane LDS program order); the Z rotation is strictly row-per-lane.
  int K, nd;
  if (tid < 64){
    K = 0; nd = 0;
    int have = 0, pj = 0;
    for (int t = 0; t < NM; ++t){
      int nj = idxm[t];
      if (rho*fabs(zz[nj]) <= tol){
        for (int q = nd; q > 0; --q) tl[q] = tl[q-1];
        tl[0] = nj; nd++;
        continue;
      }
      if (!have){ pj = nj; have = 1; continue; }
      {
        double sZ = zz[pj], cZ = zz[nj];
        double tau2 = slapy2(cZ, sZ);
        double tgap = dloc[nj] - dloc[pj];
        cZ /= tau2; sZ = -sZ/tau2;
        if (fabs(tgap*cZ*sZ) <= tol){
          zz[nj] = tau2; zz[pj] = 0.0;
          if (tid < NM){
            double xq = Z[tid*LD + pj], yq = Z[tid*LD + nj];
            Z[tid*LD + pj] = cZ*xq + sZ*yq;
            Z[tid*LD + nj] = cZ*yq - sZ*xq;
          }
          double t2 = dloc[pj]*cZ*cZ + dloc[nj]*sZ*sZ;
          double t3 = dloc[pj]*sZ*sZ + dloc[nj]*cZ*cZ;
          dloc[nj] = t3; dloc[pj] = t2;
          for (int q = nd; q > 0; --q) tl[q] = tl[q-1];
          tl[0] = pj; nd++;
          { int q = 0;
            while (q+1 < nd && dloc[tl[q]] < dloc[tl[q+1]]){
              int tt = tl[q]; tl[q] = tl[q+1]; tl[q+1] = tt; q++;
            } }
          pj = nj;
        } else {
          sv[K] = pj; dl[K] = dloc[pj]; ww[K] = zz[pj]; K++;
          pj = nj;
        }
      }
    }
    sv[K] = pj; dl[K] = dloc[pj]; ww[K] = zz[pj]; K++;
    if (tid == 0){ s_kn[0] = K; s_kn[1] = nd; }
  }
  __syncthreads();
  K = s_kn[0]; nd = s_kn[1];

  // ---- secular equation roots: 4-lane group per root j4 ----
  if (j4 < K){
    double dj = dl[j4];
    // register-cache this lane's terms; pad with inert entries so the inner
    // loops fully unroll (independent fp64 divides pipeline instead of chaining)
    double dlr[Q], wr[Q];
    double zs2p = 0.0;
    #pragma unroll
    for (int t = 0; t < Q; ++t){
      int i = part + 4*t;
      if (i < K){ double wv = ww[i]; dlr[t] = dl[i]; wr[t] = rho*wv*wv; zs2p += wv*wv; }
      else      { dlr[t] = 1.0e300; wr[t] = 0.0; }
    }
    zs2p += __shfl_xor(zs2p, 1); zs2p += __shfl_xor(zs2p, 2);
    double lo = 0.0, hi = (j4 < K-1) ? (dl[j4+1]-dj) : rho*zs2p;
    for (int it = 0; it < 24; ++it){
      double mid = 0.5*(lo+hi);
      if (mid == lo || mid == hi) break;
      double fvp = 0.0;
      #pragma unroll
      for (int t = 0; t < Q; ++t) fvp += wr[t]/((dlr[t]-dj) - mid);
      fvp += __shfl_xor(fvp, 1); fvp += __shfl_xor(fvp, 2);
      double fv = 1.0 + fvp;
      if (fv < 0.0) lo = mid; else hi = mid;
    }
    double muv = 0.5*(lo+hi);
    for (int it = 0; it < 14; ++it){
      double fvp = 0.0, fpp = 0.0;
      #pragma unroll
      for (int t = 0; t < Q; ++t){
        double den = (dlr[t]-dj) - muv;
        double inv = 1.0/den;
        double tq = wr[t]*inv;
        fvp += tq; fpp += tq*inv;
      }
      fvp += __shfl_xor(fvp, 1); fvp += __shfl_xor(fvp, 2);
      fpp += __shfl_xor(fpp, 1); fpp += __shfl_xor(fpp, 2);
      double fv = 1.0 + fvp;
      if (fv == 0.0) break;
      if (fv < 0.0) lo = muv; else hi = muv;
      double mn = muv - fv/fpp;
      if (!(mn > lo && mn < hi)) mn = 0.5*(lo+hi);
      if (mn == muv) break;
      muv = mn;
    }
    if (part == 0) mu[j4] = muv;
  }
  __syncthreads();

  // ---- Gu z-tilde (slaed3 sign convention), 4-way product split ----
  if (j4 < K){
    double dj = dl[j4];
    double pp = 1.0;
    for (int i2 = part; i2 < K; i2 += 4){
      if (i2 == j4) continue;
      double dij = dj - dl[i2];
      pp *= (dij - mu[i2])/dij;
    }
    pp *= __shfl_xor(pp, 1); pp *= __shfl_xor(pp, 2);
    double prod = -mu[j4]*pp;
    if (part == 0) wt[j4] = fsign(sqrt(fmax(-prod, 0.0)), ww[j4]);
  }
  __syncthreads();

  // ---- final permutation: slamrg(K asc, nd tail traversed backward) ----
  // Redundant-uniform: reads only barrier-stable data, writes same values.
  {
    int a = 0, q = nd-1, t = 0;
    while (a < K && q >= 0){
      if (dl[a]+mu[a] <= dloc[tl[q]]) { fperm[t++] = a; a++; }
      else { fperm[t++] = K+q; q--; }
    }
    while (a < K)  { fperm[t++] = a; a++; }
    while (q >= 0) { fperm[t++] = K+q; q--; }
  }
  __syncthreads();

  // ---- assemble new columns (4 lanes per final column, strided rows) ----
  double colr[Q]; double dnj = 0.0;
  if (j4 < NM){
    int src = fperm[j4];
    if (src < K){
      double muj = mu[src];
      double ds  = dl[src];
      double nrmp = 0.0;
      for (int i = part; i < K; i += 4){
        double del = (dl[i]-ds) - muj;
        double qv = wt[i]/del;
        nrmp += qv*qv;
      }
      nrmp += __shfl_xor(nrmp, 1); nrmp += __shfl_xor(nrmp, 2);
      double invn = 1.0/sqrt(nrmp);
      #pragma unroll
      for (int rr = 0; rr < Q; ++rr) colr[rr] = 0.0;
      for (int i = 0; i < K; ++i){
        double del = (dl[i]-ds) - muj;
        double sval = (wt[i]/del)*invn;
        int cq = sv[i];
        #pragma unroll
        for (int rr = 0; rr < Q; ++rr) colr[rr] += Z[(part+4*rr)*LD + cq]*sval;
      }
      dnj = ds + muj;
    } else {
      int tq2 = tl[src-K];
      #pragma unroll
      for (int rr = 0; rr < Q; ++rr) colr[rr] = Z[(part+4*rr)*LD + tq2];
      dnj = dloc[tq2];
    }
  }
  __syncthreads();
  if (j4 < NM){
    #pragma unroll
    for (int rr = 0; rr < Q; ++rr) Z[(part+4*rr)*LD + j4] = colr[rr];
    if (part == 0) dloc[j4] = dnj;
  }
  __syncthreads();
}

// ---------------- Phase A: Gram + channel sums ----------------
// R5: 32-row LDS tiles + register prefetch. Load of tile k+1 is issued right
// after the LDS write barrier, so its ~500-900cy HBM latency overlaps the
// ~1800cy compute on tile k (2 blocks/CU can't hide it via TLP alone).
__global__ __launch_bounds__(256) void cov_kernel(const float* __restrict__ x,
                                                  double* __restrict__ gram,
                                                  double* __restrict__ chsum)
{
  __shared__ __align__(16) float tile[32][64];
  const int b   = blockIdx.x >> 5;
  const int ch  = blockIdx.x & 31;
  const int tid = threadIdx.x;
  const int ti = tid >> 4, tj = tid & 15;
  const int lrow = tid >> 4, lf4 = tid & 15;
  const int cch = tid & 63, crr = tid >> 6;
  float acc[4][4];
  #pragma unroll
  for (int a = 0; a < 4; ++a)
    #pragma unroll
    for (int c = 0; c < 4; ++c) acc[a][c] = 0.f;
  float csum = 0.f;
  const float* xb = x + ((size_t)b*65536 + (size_t)ch*2048)*64;
  float4 v0 = *(const float4*)(xb + (size_t)(lrow     )*64 + lf4*4);
  float4 v1 = *(const float4*)(xb + (size_t)(lrow + 16)*64 + lf4*4);
  for (int r0 = 0; r0 < 2048; r0 += 32){
    __syncthreads();
    *(float4*)&tile[lrow][lf4*4]      = v0;
    *(float4*)&tile[16 + lrow][lf4*4] = v1;
    __syncthreads();
    if (r0 + 32 < 2048){
      v0 = *(const float4*)(xb + (size_t)(r0 + 32 + lrow)*64 + lf4*4);
      v1 = *(const float4*)(xb + (size_t)(r0 + 48 + lrow)*64 + lf4*4);
    }
    #pragma unroll
    for (int rr = 0; rr < 32; ++rr){
      float4 xi = *(const float4*)&tile[rr][4*ti];
      float4 xj = *(const float4*)&tile[rr][4*tj];
      acc[0][0] += xi.x*xj.x; acc[0][1] += xi.x*xj.y; acc[0][2] += xi.x*xj.z; acc[0][3] += xi.x*xj.w;
      acc[1][0] += xi.y*xj.x; acc[1][1] += xi.y*xj.y; acc[1][2] += xi.y*xj.z; acc[1][3] += xi.y*xj.w;
      acc[2][0] += xi.z*xj.x; acc[2][1] += xi.z*xj.y; acc[2][2] += xi.z*xj.z; acc[2][3] += xi.z*xj.w;
      acc[3][0] += xi.w*xj.x; acc[3][1] += xi.w*xj.y; acc[3][2] += xi.w*xj.z; acc[3][3] += xi.w*xj.w;
    }
    #pragma unroll
    for (int rr2 = 0; rr2 < 8; ++rr2) csum += tile[crr + rr2*4][cch];
  }
  double* gb = gram + (size_t)b*4096;
  #pragma unroll
  for (int a = 0; a < 4; ++a)
    #pragma unroll
    for (int c = 0; c < 4; ++c)
      atomicAdd(&gb[(4*ti+a)*64 + (4*tj+c)], (double)acc[a][c]);
  atomicAdd(&chsum[b*64 + cch], (double)csum);
}

// ---------------- Phase B1: ssytd2 (dense symmetric trailing update in LDS) ----------------
// R5: inner loops run the FULL 0..63 range with #pragma unroll. vv_/wv_ are
// exactly 0 for c2 <= i and rows tid < i+1 have vval = wv_[tid] = 0, so every
// added term is identically zero — results unchanged, but the LDS reads now
// pipeline instead of forming a 64-deep dependent lgkmcnt chain per step.
__global__ __launch_bounds__(64) void tridiag_kernel(const double* __restrict__ gram,
                                                     const double* __restrict__ chsum,
                                                     double* __restrict__ dG,
                                                     double* __restrict__ eG,
                                                     double* __restrict__ tauG,
                                                     double* __restrict__ VlG,
                                                     float* __restrict__ meanG)
{
  __shared__ double As[64*65];
  __shared__ double vv_[64], wv_[64], mu_s[64], es_s[64], tau_s[64];
  const int b = blockIdx.x;
  const int tid = threadIdx.x;
  const double* gb = gram + (size_t)b*4096;

  double mval = chsum[b*64+tid]*(1.0/65536.0);
  meanG[b*64+tid] = (float)mval;
  mu_s[tid] = mval;
  __syncthreads();
  for (int idx = tid; idx < 4096; idx += 64){
    int i = idx >> 6, j = idx & 63;
    As[i*65+j] = (gb[idx] - 65536.0*mu_s[i]*mu_s[j])*(1.0/65535.0);
  }
  __syncthreads();

  for (int i = 0; i < 63; ++i){
    double alpha = As[(i+1)*65+i];
    double xv0 = (tid >= i+2) ? As[tid*65+i] : 0.0;
    double xn2 = wave_sum(xv0*xv0);
    if (xn2 == 0.0){
      es_s[i] = alpha; tau_s[i] = 0.0;
      VlG[((size_t)b*63 + i)*64 + tid] = 0.0;
      __syncthreads();
      continue;
    }
    double xnorm = sqrt(xn2);
    double betav = -fsign(slapy2(alpha, xnorm), alpha);
    double taui  = (betav-alpha)/betav;
    double invs  = 1.0/(alpha-betav);
    double vval = (tid == i+1) ? 1.0 : ((tid >= i+2) ? xv0*invs : 0.0);
    vv_[tid] = vval;
    VlG[((size_t)b*63 + i)*64 + tid] = vval;   // coalesced reflector store (transposed layout)
    __syncthreads();
    // full-range unrolled dot (vv_[c2]=0 for c2<=i); 4-way split accumulators
    // let the fp64 FMAs pipeline (reassociation ~1e-16, far below the fp32
    // replication noise already accepted by the harness threshold).
    double x0 = 0.0, x1 = 0.0, x2 = 0.0, x3 = 0.0;
    #pragma unroll
    for (int c2 = 0; c2 < 64; c2 += 4){
      x0 += As[tid*65+c2+0]*vv_[c2+0];
      x1 += As[tid*65+c2+1]*vv_[c2+1];
      x2 += As[tid*65+c2+2]*vv_[c2+2];
      x3 += As[tid*65+c2+3]*vv_[c2+3];
    }
    double xvr = ((x0+x1)+(x2+x3))*taui;
    double dot = wave_sum((tid >= i+1) ? xvr*vval : 0.0);
    double alf = -0.5*taui*dot;
    wv_[tid] = (tid >= i+1) ? (xvr + alf*vval) : 0.0;
    __syncthreads();
    {
      double vr = vval, wr = wv_[tid];   // both 0 for tid < i+1 -> row no-op
      #pragma unroll
      for (int c2 = 0; c2 < 64; ++c2)
        As[tid*65+c2] -= vr*wv_[c2] + wr*vv_[c2];
    }
    es_s[i] = betav; tau_s[i] = taui;
    __syncthreads();
  }
  dG[b*64+tid]   = As[tid*65+tid];
  eG[b*64+tid]   = (tid < 63) ? es_s[tid]  : 0.0;
  tauG[b*64+tid] = (tid < 63) ? tau_s[tid] : 0.0;
}

// ---------------- Phase B2: 64 independent 16x16 steqr ----------------
__global__ __launch_bounds__(64) void steqr_kernel(double* __restrict__ dG,
                                                   const double* __restrict__ eG,
                                                   double* __restrict__ Zg)
{
  __shared__ double Zt[16*17];
  __shared__ double dd[16], ee[16], wc[20], wsn[20];
  const int b = blockIdx.x >> 2, s = blockIdx.x & 3;
  const int tid = threadIdx.x;

  // load tridiag segment + D&C rank-one cut adjustments
  {
    double dv = (tid < 16) ? dG[b*64 + 16*s + tid] : 0.0;
    if (tid == 0  && s > 0) dv -= fabs(eG[b*64 + 16*s - 1]);
    if (tid == 15 && s < 3) dv -= fabs(eG[b*64 + 16*s + 15]);
    if (tid < 16) dd[tid] = dv;
    if (tid < 15) ee[tid] = eG[b*64 + 16*s + tid];
    if (tid == 15) ee[15] = 0.0;
  }
  for (int idx = tid; idx < 16*17; idx += 64) Zt[idx] = 0.0;
  __syncthreads();
  if (tid < 16) Zt[tid*17+tid] = 1.0;
  __syncthreads();

  steqr16<17>(dd, ee, Zt, tid, wc, wsn);
  __syncthreads();

  // store compact 16x16 block + updated d
  for (int idx = tid; idx < 256; idx += 64){
    int r = idx >> 4, c = idx & 15;
    Zg[(size_t)b*4096 + s*256 + idx] = Zt[r*17+c];
  }
  if (tid < 16) dG[b*64 + 16*s + tid] = dd[tid];
}

// ---------------- Phase B3: two independent 16+16 merges (256 thr) ----------------
__global__ __launch_bounds__(256) void merge16_kernel(double* __restrict__ Zg,
                                                      double* __restrict__ dG,
                                                      const double* __restrict__ eG)
{
  __shared__ double Z32[32*33];
  __shared__ double dloc[32];
  __shared__ double zz[32], dl[32], ww[32], mu[32], wt[32];
  __shared__ int idxm[32], sv[32], tl[32], fp[32];
  const int b = blockIdx.x >> 1, h = blockIdx.x & 1;
  const int tid = threadIdx.x;

  for (int idx = tid; idx < 32*33; idx += 256) Z32[idx] = 0.0;
  if (tid < 32) dloc[tid] = dG[b*64 + 32*h + tid];
  __syncthreads();
  {
    int idx = tid;  // exactly 256 elements per 16x16 block
    int r = idx >> 4, c = idx & 15;
    Z32[r*33 + c]           = Zg[(size_t)b*4096 + (2*h)*256   + idx];
    Z32[(16+r)*33 + (16+c)] = Zg[(size_t)b*4096 + (2*h+1)*256 + idx];
  }
  __syncthreads();

  double rho_in = eG[b*64 + 32*h + 15];
  merge_dc<16,33>(Z32, dloc, rho_in, tid, zz, dl, ww, mu, wt, idxm, sv, tl, fp);

  // store 32x32 result to the upper half of Zg[b] (disjoint from the inputs)
  for (int idx = tid; idx < 1024; idx += 256){
    int r = idx >> 5, c = idx & 31;
    Zg[(size_t)b*4096 + 2048 + h*1024 + idx] = Z32[r*33 + c];
  }
  if (tid < 32) dG[b*64 + 32*h + tid] = dloc[tid];
}

// ---------------- Phase B4: 32+32 merge + back-transform + output V (256 thr) ----------------
__global__ __launch_bounds__(256) void merge32_bt_kernel(const double* __restrict__ Zg,
                                                         double* __restrict__ dG,
                                                         const double* __restrict__ eG,
                                                         const double* __restrict__ tauG,
                                                         const double* __restrict__ VlG,
                                                         float* __restrict__ Vt)
{
  __shared__ double Z64[64*65];
  __shared__ double Vl_s[63*64];
  __shared__ double dloc[64], tau_l[64];
  __shared__ double zz[64], dl[64], ww[64], mu[64], wt[64];
  __shared__ int idxm[64], sv[64], tl[64], fp[64];
  const int b = blockIdx.x;
  const int tid = threadIdx.x;

  for (int idx = tid; idx < 64*65; idx += 256) Z64[idx] = 0.0;
  if (tid < 64){ dloc[tid] = dG[b*64 + tid]; tau_l[tid] = tauG[b*64 + tid]; }
  // stage all reflectors once (kills per-step uniform global-load latency chains)
  for (int idx = tid; idx < 63*64; idx += 256) Vl_s[idx] = VlG[(size_t)b*63*64 + idx];
  __syncthreads();
  for (int idx = tid; idx < 1024; idx += 256){
    int r = idx >> 5, c = idx & 31;
    Z64[r*65 + c]           = Zg[(size_t)b*4096 + 2048 + idx];
    Z64[(32+r)*65 + (32+c)] = Zg[(size_t)b*4096 + 3072 + idx];
  }
  __syncthreads();

  double rho_in = eG[b*64 + 31];
  merge_dc<32,65>(Z64, dloc, rho_in, tid, zz, dl, ww, mu, wt, idxm, sv, tl, fp);

  // back-transform: Z := H1...H63 * Z, entirely in registers.
  // Lane (jc = tid>>2, part = tid&3) owns rows {part+4*rr} of column jc.
  // Vl rows are zero for r <= i and 1 at r == i+1, so the unguarded FMA form
  // reproduces the original guarded loops exactly.
  {
    const int jc = tid >> 2, part = tid & 3;
    double z[16];
    #pragma unroll
    for (int rr = 0; rr < 16; ++rr) z[rr] = Z64[(part + 4*rr)*65 + jc];
    for (int i = 62; i >= 0; --i){
      double taui = tau_l[i];
      if (taui == 0.0) continue;
      double vir[16];
      #pragma unroll
      for (int rr = 0; rr < 16; ++rr) vir[rr] = Vl_s[i*64 + part + 4*rr];
      double w0 = 0.0, w1 = 0.0;
      #pragma unroll
      for (int rr = 0; rr < 16; rr += 2){ w0 += vir[rr]*z[rr]; w1 += vir[rr+1]*z[rr+1]; }
      double w = w0 + w1;
      w += __shfl_xor(w, 1);
      w += __shfl_xor(w, 2);
      w *= taui;
      #pragma unroll
      for (int rr = 0; rr < 16; ++rr) z[rr] -= vir[rr]*w;
    }
    // each lane reads/writes only its own (row,col) elements -> no barrier needed
    #pragma unroll
    for (int rr = 0; rr < 16; ++rr) Z64[(part + 4*rr)*65 + jc] = z[rr];
  }
  __syncthreads();

  // Vt[b][c][k] = V[c][63-k]  (descending top-32)
  for (int idx = tid; idx < 2048; idx += 256){
    int c2 = idx >> 5, k = idx & 31;
    Vt[(size_t)b*2048 + idx] = (float)Z64[c2*65 + (63-k)];
  }
}

// ---------------- Phase C: projection ----------------
// R5: Vs read as float4 (b128 broadcast) — 512 LDS reads/thread instead of 2048.
__global__ __launch_bounds__(256) void proj_kernel(const float* __restrict__ x,
                                                   const float* __restrict__ Vt,
                                                   const float* __restrict__ meanf,
                                                   float* __restrict__ out)
{
  __shared__ __align__(16) float Vs[64][32];
  __shared__ float ms[64];
  const int b = blockIdx.x >> 8;
  const int rb = blockIdx.x & 255;
  const int tid = threadIdx.x;
  for (int idx = tid; idx < 2048; idx += 256) ((float*)Vs)[idx] = Vt[(size_t)b*2048 + idx];
  if (tid < 64) ms[tid] = meanf[b*64+tid];
  __syncthreads();
  const size_t row = (size_t)b*65536 + (size_t)rb*256 + tid;
  const float4* xr = (const float4*)(x + row*64);
  float acc[32];
  #pragma unroll
  for (int k = 0; k < 32; ++k) acc[k] = 0.f;
  #pragma unroll
  for (int c4 = 0; c4 < 16; ++c4){
    float4 xv = xr[c4];
    float t0 = xv.x - ms[4*c4+0];
    float t1 = xv.y - ms[4*c4+1];
    float t2 = xv.z - ms[4*c4+2];
    float t3 = xv.w - ms[4*c4+3];
    #pragma unroll
    for (int k4 = 0; k4 < 8; ++k4){
      const float4 a0 = *(const float4*)&Vs[4*c4+0][4*k4];
      const float4 a1 = *(const float4*)&Vs[4*c4+1][4*k4];
      const float4 a2 = *(const float4*)&Vs[4*c4+2][4*k4];
      const float4 a3 = *(const float4*)&Vs[4*c4+3][4*k4];
      acc[4*k4+0] += t0*a0.x + t1*a1.x + t2*a2.x + t3*a3.x;
      acc[4*k4+1] += t0*a0.y + t1*a1.y + t2*a2.y + t3*a3.y;
      acc[4*k4+2] += t0*a0.z + t1*a1.z + t2*a2.z + t3*a3.z;
      acc[4*k4+3] += t0*a0.w + t1*a1.w + t2*a2.w + t3*a3.w;
    }
  }
  float4* op = (float4*)(out + row*32);
  #pragma unroll
  for (int k4 = 0; k4 < 8; ++k4)
    op[k4] = make_float4(acc[4*k4], acc[4*k4+1], acc[4*k4+2], acc[4*k4+3]);
}

extern "C" void kernel_launch(void* const* d_in, const int* in_sizes, int n_in,
                              void* d_out, int out_size, void* d_ws, size_t ws_size,
                              hipStream_t stream)
{
  const float* x = (const float*)d_in[0];
  float* out = (float*)d_out;
  char* ws = (char*)d_ws;
  // ws layout (bytes):
  //   [0,       524288) gram 16x64x64 dbl (atomics; zeroed) -> reused as Zg after tridiag
  //   [524288,  532480) chsum 16x64 dbl (atomics; zeroed)
  //   [532480,  540672) dG   16x64 dbl
  //   [540672,  548864) eG   16x64 dbl
  //   [548864,  557056) tauG 16x64 dbl
  //   [557056, 1073152) VlG  16x63x64 dbl (reflectors, transposed: Vl[b][i][r])
  //   [1073152,1204224) Vt   16x64x32 f32
  //   [1204224,1208320) mean 16x64 f32
  double* gram  = (double*)(ws);
  double* Zg    = (double*)(ws);             // alias: gram dead after tridiag_kernel
  double* chsum = (double*)(ws + 524288);
  double* dG    = (double*)(ws + 532480);
  double* eG    = (double*)(ws + 540672);
  double* tauG  = (double*)(ws + 548864);
  double* VlG   = (double*)(ws + 557056);
  float*  Vt    = (float*) (ws + 1073152);
  float*  mf    = (float*) (ws + 1204224);

  hipMemsetAsync(ws, 0, 532480, stream);
  cov_kernel     <<<dim3(512),  dim3(256), 0, stream>>>(x, gram, chsum);
  tridiag_kernel <<<dim3(16),   dim3(64),  0, stream>>>(gram, chsum, dG, eG, tauG, VlG, mf);
  steqr_kernel   <<<dim3(64),   dim3(64),  0, stream>>>(dG, eG, Zg);
  merge16_kernel <<<dim3(32),   dim3(256), 0, stream>>>(Zg, dG, eG);
  merge32_bt_kernel<<<dim3(16), dim3(256), 0, stream>>>(Zg, dG, eG, tauG, VlG, Vt);
  proj_kernel    <<<dim3(4096), dim3(256), 0, stream>>>(x, Vt, mf, out);
}

// Round 5
// 981.348 us; speedup vs baseline: 1.4343x; 1.0540x over previous
//
#include <hip/hip_runtime.h>
#include <hip/hip_bf16.h>

// PCA layer: B=16, N=65536 (256x256), C=64, K=32.
// LAPACK ssyevd replication (ssytd2 + sstedc D&C + back-transform) in fp64 so
// eigenvector SIGNS match the numpy/LAPACK reference.
// R2: eigh split into 4 kernels; matrix in LDS; reflectors via uniform global loads.
// R3: merge kernels widened to 256 threads; 4 lanes cooperate per column/root.
// R4 FIX: slaed2 deflation scan runs on wave 0 only (cross-wave redundant
//     execution raced at 256 threads).
// R5: cov 32-row tiles + register prefetch; tridiag full-range unrolled loops;
//     proj float4 LDS reads.
// R6: tridiag widened to 256 threads (4 waves). Wave w owns columns 16w..16w+15;
//     every wave holds all 64 rows, so the two wave-wide reductions (xn2, dot)
//     are computed redundantly per-wave (bit-identical -> uniform branches, no
//     cross-wave traffic). Only the A.v dot crosses waves: 16-col partials to
//     part_s[w*64+row] + one barrier + identical 4-term combine. Cuts the
//     per-step serial issue (ds ops and fp64 FMAs) 4x; tridiag was latency-bound
//     at VALUBusy 0.33% with one wave doing 63 dependent Householder steps.
// R7: resubmit of R6 — previous run died to a container-infrastructure failure
//     ("MI355X container failed twice"), the kernel was never benched.

__device__ __forceinline__ double fsign(double a, double b){ return (b >= 0.0) ? fabs(a) : -fabs(a); }
__device__ __forceinline__ double slapy2(double x, double y){ return sqrt(x*x + y*y); }

__device__ __forceinline__ void slartg(double f, double g, double& cs, double& sn, double& r){
  if (g == 0.0){ cs = 1.0; sn = 0.0; r = f; }
  else if (f == 0.0){ cs = 0.0; sn = fsign(1.0, g); r = fabs(g); }
  else {
    double d = sqrt(f*f + g*g);
    cs = fabs(f)/d;
    r  = fsign(d, f);
    sn = g/r;
  }
}

__device__ __forceinline__ void slaev2(double a, double b, double c,
                                       double& rt1, double& rt2, double& cs1, double& sn1){
  double sm = a + c, df = a - c, adf = fabs(df), tb = b + b, ab = fabs(tb);
  double acmx, acmn, rt, cs, ct, acs, tn; int sgn1, sgn2;
  if (fabs(a) > fabs(c)) { acmx = a; acmn = c; } else { acmx = c; acmn = a; }
  if (adf > ab)      rt = adf*sqrt(1.0 + (ab/adf)*(ab/adf));
  else if (adf < ab) rt = ab*sqrt(1.0 + (adf/ab)*(adf/ab));
  else               rt = ab*sqrt(2.0);
  if (sm < 0.0){ rt1 = 0.5*(sm - rt); sgn1 = -1; rt2 = (acmx/rt1)*acmn - (b/rt1)*b; }
  else if (sm > 0.0){ rt1 = 0.5*(sm + rt); sgn1 = 1; rt2 = (acmx/rt1)*acmn - (b/rt1)*b; }
  else { rt1 = 0.5*rt; rt2 = -0.5*rt; sgn1 = 1; }
  if (df >= 0.0){ cs = df + rt; sgn2 = 1; } else { cs = df - rt; sgn2 = -1; }
  acs = fabs(cs);
  if (acs > ab){ ct = -tb/cs; sn1 = 1.0/sqrt(1.0 + ct*ct); cs1 = ct*sn1; }
  else {
    if (ab == 0.0){ cs1 = 1.0; sn1 = 0.0; }
    else { tn = -cs/tb; cs1 = 1.0/sqrt(1.0 + tn*tn); sn1 = tn*cs1; }
  }
  if (sgn1 == sgn2){ tn = cs1; cs1 = -sn1; sn1 = tn; }
}

__device__ __forceinline__ double wave_sum(double v){
  #pragma unroll
  for (int off = 32; off > 0; off >>= 1) v += __shfl_xor(v, off);
  return v;
}

// ---------- ssteqr('I') on a standalone 16x16 tile (ld=LDZ), faithful transcription ----------
template<int LDZ>
__device__ void steqr16(double* dd, double* ee, double* Zt, int tid,
                        double* wc, double* wsn)
{
#define DQ(i) dd[(i)-1]
#define EQ(i) ee[(i)-1]
#define ZT(r,c) Zt[(r)*LDZ+(c)]
  const int n = 16;
  const double eps = 5.9604644775390625e-8;     // slamch('E') fp32
  const double eps2 = eps*eps;
  const double safmin = 1.1754943508222875e-38; // slamch('S') fp32
  const int nmaxit = n*30;
  int jtot = 0, l1 = 1, nm1 = n-1;
  int l, lsv, lend, lendsv, m, i;
  double p, g, r, s, c, f, b2, rt1, rt2, anorm, tst;

L10:
  if (l1 > n) goto L160;
  if (l1 > 1) EQ(l1-1) = 0.0;
  if (l1 <= nm1){
    for (m = l1; m <= nm1; ++m){
      tst = fabs(EQ(m));
      if (tst == 0.0) goto L30;
      if (tst <= (sqrt(fabs(DQ(m)))*sqrt(fabs(DQ(m+1))))*eps){ EQ(m) = 0.0; goto L30; }
    }
  }
  m = n;
L30:
  l = l1; lsv = l; lend = m; lendsv = lend; l1 = m+1;
  if (lend == l) goto L10;
  anorm = 0.0;
  for (i = l; i <= lend; ++i) anorm = fmax(anorm, fabs(DQ(i)));
  for (i = l; i <  lend; ++i) anorm = fmax(anorm, fabs(EQ(i)));
  if (anorm == 0.0) goto L10;
  if (fabs(DQ(lend)) < fabs(DQ(l))){ lend = lsv; l = lendsv; }
  if (lend > l){
    // ------------------ QL iteration ------------------
L40:
    if (l != lend){
      for (m = l; m <= lend-1; ++m){
        tst = fabs(EQ(m)); tst = tst*tst;
        if (tst <= (eps2*fabs(DQ(m)))*fabs(DQ(m+1)) + safmin) goto L60;
      }
    }
    m = lend;
L60:
    if (m < lend) EQ(m) = 0.0;
    p = DQ(l);
    if (m == l) goto L80;
    if (m == l+1){
      slaev2(DQ(l), EQ(l), DQ(l+1), rt1, rt2, c, s);
      if (tid < 16){
        double t = ZT(tid, l);
        ZT(tid, l)   = c*t - s*ZT(tid, l-1);
        ZT(tid, l-1) = s*t + c*ZT(tid, l-1);
      }
      DQ(l) = rt1; DQ(l+1) = rt2; EQ(l) = 0.0;
      l += 2;
      if (l <= lend) goto L40;
      goto L140;
    }
    if (jtot == nmaxit) goto L140;
    jtot++;
    g = (DQ(l+1)-p)/(2.0*EQ(l));
    r = slapy2(g, 1.0);
    g = DQ(m) - p + (EQ(l)/(g + fsign(r, g)));
    s = 1.0; c = 1.0; p = 0.0;
    for (i = m-1; i >= l; --i){
      f = s*EQ(i); b2 = c*EQ(i);
      slartg(g, f, c, s, r);
      if (i != m-1) EQ(i+1) = r;
      g = DQ(i+1) - p;
      r = (DQ(i)-g)*s + 2.0*c*b2;
      p = s*r;
      DQ(i+1) = g + p;
      g = c*r - b2;
      wc[i] = c; wsn[i] = -s;
    }
    for (int i2 = m-1; i2 >= l; --i2){   // slasr 'R','V','B'
      double cc = wc[i2], ssv = wsn[i2];
      if (tid < 16){
        double t = ZT(tid, i2);
        ZT(tid, i2)   = cc*t - ssv*ZT(tid, i2-1);
        ZT(tid, i2-1) = ssv*t + cc*ZT(tid, i2-1);
      }
    }
    DQ(l) = DQ(l) - p;
    EQ(l) = g;
    goto L40;
L80:
    DQ(l) = p;
    l++;
    if (l <= lend) goto L40;
    goto L140;
  } else {
    // ------------------ QR iteration ------------------
L90:
    if (l != lend){
      for (m = l; m >= lend+1; --m){
        tst = fabs(EQ(m-1)); tst = tst*tst;
        if (tst <= (eps2*fabs(DQ(m)))*fabs(DQ(m-1)) + safmin) goto L110;
      }
    }
    m = lend;
L110:
    if (m > lend) EQ(m-1) = 0.0;
    p = DQ(l);
    if (m == l) goto L130;
    if (m == l-1){
      slaev2(DQ(l-1), EQ(l-1), DQ(l), rt1, rt2, c, s);
      if (tid < 16){
        double t = ZT(tid, l-1);
        ZT(tid, l-1) = c*t - s*ZT(tid, l-2);
        ZT(tid, l-2) = s*t + c*ZT(tid, l-2);
      }
      DQ(l-1) = rt1; DQ(l) = rt2; EQ(l-1) = 0.0;
      l -= 2;
      if (l >= lend) goto L90;
      goto L140;
    }
    if (jtot == nmaxit) goto L140;
    jtot++;
    g = (DQ(l-1)-p)/(2.0*EQ(l-1));
    r = slapy2(g, 1.0);
    g = DQ(m) - p + (EQ(l-1)/(g + fsign(r, g)));
    s = 1.0; c = 1.0; p = 0.0;
    for (i = m; i <= l-1; ++i){
      f = s*EQ(i); b2 = c*EQ(i);
      slartg(g, f, c, s, r);
      if (i != m) EQ(i-1) = r;
      g = DQ(i) - p;
      r = (DQ(i+1)-g)*s + 2.0*c*b2;
      p = s*r;
      DQ(i) = g + p;
      g = c*r - b2;
      wc[i] = c; wsn[i] = s;
    }
    for (int i2 = m; i2 <= l-1; ++i2){   // slasr 'R','V','F'
      double cc = wc[i2], ssv = wsn[i2];
      if (tid < 16){
        double t = ZT(tid, i2);
        ZT(tid, i2)   = cc*t - ssv*ZT(tid, i2-1);
        ZT(tid, i2-1) = ssv*t + cc*ZT(tid, i2-1);
      }
    }
    DQ(l) = DQ(l) - p;
    EQ(l-1) = g;
    goto L90;
L130:
    DQ(l) = p;
    l--;
    if (l >= lend) goto L90;
    goto L140;
  }
L140:
  if (jtot < nmaxit) goto L10;
L160:
  // selection sort ascending with column swaps (as in ssteqr)
  for (int ii = 2; ii <= n; ++ii){
    int i3 = ii-1, k2 = i3;
    p = DQ(i3);
    for (int j = ii; j <= n; ++j) if (DQ(j) < p){ k2 = j; p = DQ(j); }
    if (k2 != i3){
      DQ(k2) = DQ(i3); DQ(i3) = p;
      if (tid < 16){
        double t = ZT(tid, i3-1);
        ZT(tid, i3-1) = ZT(tid, k2-1);
        ZT(tid, k2-1) = t;
      }
    }
  }
#undef DQ
#undef EQ
#undef ZT
}

// ---------- slaed1/slaed2/slaed3 merge on a standalone NMxNM tile ----------
// Requires blockDim.x == 256. Deflation scan: wave 0 only (see R4 note at top).
// All other phases: 4 lanes (part = tid&3) cooperate per column/root j4 = tid>>2;
// strided rows r = part+4*rr are bank-conflict-free; 4-lane shuffle reductions are
// bit-identical across the group (commutative fp adds) so branches stay uniform.
template<int N1, int LD>
__device__ void merge_dc(double* Z, double* dloc, double rho_in, int tid,
                         double* zz, double* dl, double* ww, double* mu, double* wt,
                         int* idxm, int* sv, int* tl, int* fperm)
{
  const int NM = 2*N1;
  const int Q  = NM/4;                 // rows / secular terms per lane
  const double eps32 = 5.9604644775390625e-8;
  const int j4 = tid >> 2, part = tid & 3;
  __shared__ int s_kn[2];

  // z-vector: last row of Q1, first row of Q2
  if (tid < N1)       zz[tid] = Z[(N1-1)*LD + tid];
  else if (tid < NM)  zz[tid] = Z[N1*LD + tid];
  __syncthreads();
  if (rho_in < 0.0 && tid >= N1 && tid < NM) zz[tid] = -zz[tid];
  __syncthreads();
  if (tid < NM) zz[tid] *= 0.70710678118654752440;
  __syncthreads();
  double rho = fabs(2.0*rho_in);

  // merged ascending order (both halves already ascending), ties -> first half.
  // Redundant on every thread; each thread later reads only entries it wrote
  // itself (per-lane LDS program order), cross-wave writes are same-value.
  {
    int i1 = 0, i2 = 0, t = 0;
    while (i1 < N1 && i2 < N1){
      if (dloc[i1] <= dloc[N1+i2]) idxm[t++] = i1++;
      else                         idxm[t++] = N1 + (i2++);
    }
    while (i1 < N1) idxm[t++] = i1++;
    while (i2 < N1) idxm[t++] = N1 + (i2++);
  }
  double dmax = 0.0, zmax = 0.0;
  for (int i = 0; i < NM; ++i){ dmax = fmax(dmax, fabs(dloc[i])); zmax = fmax(zmax, fabs(zz[i])); }
  double tol = 8.0*eps32*fmax(dmax, zmax);

  if (rho*zmax <= tol){
    // everything deflates: just sort ascending
    double colr[Q]; double dnj = 0.0;
    if (j4 < NM){
      int s0 = idxm[j4];
      dnj = dloc[s0];
      #pragma unroll
      for (int rr = 0; rr < Q; ++rr) colr[rr] = Z[(part+4*rr)*LD + s0];
    }
    __syncthreads();
    if (j4 < NM){
      #pragma unroll
      for (int rr = 0; rr < Q; ++rr) Z[(part+4*rr)*LD + j4] = colr[rr];
      if (part == 0) dloc[j4] = dnj;
    }
    __syncthreads();
    return;
  }

  // ---- slaed2 deflation scan: WAVE 0 ONLY (mutates zz/dloc/tl/Z mid-scan;
  //      cross-wave redundant execution races — R3 bug). Within one wave each
  //      lane redundantly performs the scalar writes itself (self-consistent by
  //      per-lane LDS program order); the Z rotation is strictly row-per-lane.
  int K, nd;
  if (tid < 64){
    K = 0; nd = 0;
    int have = 0, pj = 0;
    for (int t = 0; t < NM; ++t){
      int nj = idxm[t];
      if (rho*fabs(zz[nj]) <= tol){
        for (int q = nd; q > 0; --q) tl[q] = tl[q-1];
        tl[0] = nj; nd++;
        continue;
      }
      if (!have){ pj = nj; have = 1; continue; }
      {
        double sZ = zz[pj], cZ = zz[nj];
        double tau2 = slapy2(cZ, sZ);
        double tgap = dloc[nj] - dloc[pj];
        cZ /= tau2; sZ = -sZ/tau2;
        if (fabs(tgap*cZ*sZ) <= tol){
          zz[nj] = tau2; zz[pj] = 0.0;
          if (tid < NM){
            double xq = Z[tid*LD + pj], yq = Z[tid*LD + nj];
            Z[tid*LD + pj] = cZ*xq + sZ*yq;
            Z[tid*LD + nj] = cZ*yq - sZ*xq;
          }
          double t2 = dloc[pj]*cZ*cZ + dloc[nj]*sZ*sZ;
          double t3 = dloc[pj]*sZ*sZ + dloc[nj]*cZ*cZ;
          dloc[nj] = t3; dloc[pj] = t2;
          for (int q = nd; q > 0; --q) tl[q] = tl[q-1];
          tl[0] = pj; nd++;
          { int q = 0;
            while (q+1 < nd && dloc[tl[q]] < dloc[tl[q+1]]){
              int tt = tl[q]; tl[q] = tl[q+1]; tl[q+1] = tt; q++;
            } }
          pj = nj;
        } else {
          sv[K] = pj; dl[K] = dloc[pj]; ww[K] = zz[pj]; K++;
          pj = nj;
        }
      }
    }
    sv[K] = pj; dl[K] = dloc[pj]; ww[K] = zz[pj]; K++;
    if (tid == 0){ s_kn[0] = K; s_kn[1] = nd; }
  }
  __syncthreads();
  K = s_kn[0]; nd = s_kn[1];

  // ---- secular equation roots: 4-lane group per root j4 ----
  if (j4 < K){
    double dj = dl[j4];
    // register-cache this lane's terms; pad with inert entries so the inner
    // loops fully unroll (independent fp64 divides pipeline instead of chaining)
    double dlr[Q], wr[Q];
    double zs2p = 0.0;
    #pragma unroll
    for (int t = 0; t < Q; ++t){
      int i = part + 4*t;
      if (i < K){ double wv = ww[i]; dlr[t] = dl[i]; wr[t] = rho*wv*wv; zs2p += wv*wv; }
      else      { dlr[t] = 1.0e300; wr[t] = 0.0; }
    }
    zs2p += __shfl_xor(zs2p, 1); zs2p += __shfl_xor(zs2p, 2);
    double lo = 0.0, hi = (j4 < K-1) ? (dl[j4+1]-dj) : rho*zs2p;
    for (int it = 0; it < 24; ++it){
      double mid = 0.5*(lo+hi);
      if (mid == lo || mid == hi) break;
      double fvp = 0.0;
      #pragma unroll
      for (int t = 0; t < Q; ++t) fvp += wr[t]/((dlr[t]-dj) - mid);
      fvp += __shfl_xor(fvp, 1); fvp += __shfl_xor(fvp, 2);
      double fv = 1.0 + fvp;
      if (fv < 0.0) lo = mid; else hi = mid;
    }
    double muv = 0.5*(lo+hi);
    for (int it = 0; it < 14; ++it){
      double fvp = 0.0, fpp = 0.0;
      #pragma unroll
      for (int t = 0; t < Q; ++t){
        double den = (dlr[t]-dj) - muv;
        double inv = 1.0/den;
        double tq = wr[t]*inv;
        fvp += tq; fpp += tq*inv;
      }
      fvp += __shfl_xor(fvp, 1); fvp += __shfl_xor(fvp, 2);
      fpp += __shfl_xor(fpp, 1); fpp += __shfl_xor(fpp, 2);
      double fv = 1.0 + fvp;
      if (fv == 0.0) break;
      if (fv < 0.0) lo = muv; else hi = muv;
      double mn = muv - fv/fpp;
      if (!(mn > lo && mn < hi)) mn = 0.5*(lo+hi);
      if (mn == muv) break;
      muv = mn;
    }
    if (part == 0) mu[j4] = muv;
  }
  __syncthreads();

  // ---- Gu z-tilde (slaed3 sign convention), 4-way product split ----
  if (j4 < K){
    double dj = dl[j4];
    double pp = 1.0;
    for (int i2 = part; i2 < K; i2 += 4){
      if (i2 == j4) continue;
      double dij = dj - dl[i2];
      pp *= (dij - mu[i2])/dij;
    }
    pp *= __shfl_xor(pp, 1); pp *= __shfl_xor(pp, 2);
    double prod = -mu[j4]*pp;
    if (part == 0) wt[j4] = fsign(sqrt(fmax(-prod, 0.0)), ww[j4]);
  }
  __syncthreads();

  // ---- final permutation: slamrg(K asc, nd tail traversed backward) ----
  // Redundant-uniform: reads only barrier-stable data, writes same values.
  {
    int a = 0, q = nd-1, t = 0;
    while (a < K && q >= 0){
      if (dl[a]+mu[a] <= dloc[tl[q]]) { fperm[t++] = a; a++; }
      else { fperm[t++] = K+q; q--; }
    }
    while (a < K)  { fperm[t++] = a; a++; }
    while (q >= 0) { fperm[t++] = K+q; q--; }
  }
  __syncthreads();

  // ---- assemble new columns (4 lanes per final column, strided rows) ----
  double colr[Q]; double dnj = 0.0;
  if (j4 < NM){
    int src = fperm[j4];
    if (src < K){
      double muj = mu[src];
      double ds  = dl[src];
      double nrmp = 0.0;
      for (int i = part; i < K; i += 4){
        double del = (dl[i]-ds) - muj;
        double qv = wt[i]/del;
        nrmp += qv*qv;
      }
      nrmp += __shfl_xor(nrmp, 1); nrmp += __shfl_xor(nrmp, 2);
      double invn = 1.0/sqrt(nrmp);
      #pragma unroll
      for (int rr = 0; rr < Q; ++rr) colr[rr] = 0.0;
      for (int i = 0; i < K; ++i){
        double del = (dl[i]-ds) - muj;
        double sval = (wt[i]/del)*invn;
        int cq = sv[i];
        #pragma unroll
        for (int rr = 0; rr < Q; ++rr) colr[rr] += Z[(part+4*rr)*LD + cq]*sval;
      }
      dnj = ds + muj;
    } else {
      int tq2 = tl[src-K];
      #pragma unroll
      for (int rr = 0; rr < Q; ++rr) colr[rr] = Z[(part+4*rr)*LD + tq2];
      dnj = dloc[tq2];
    }
  }
  __syncthreads();
  if (j4 < NM){
    #pragma unroll
    for (int rr = 0; rr < Q; ++rr) Z[(part+4*rr)*LD + j4] = colr[rr];
    if (part == 0) dloc[j4] = dnj;
  }
  __syncthreads();
}

// ---------------- Phase A: Gram + channel sums ----------------
// R5: 32-row LDS tiles + register prefetch. Load of tile k+1 is issued right
// after the LDS write barrier, so its ~500-900cy HBM latency overlaps the
// ~1800cy compute on tile k (2 blocks/CU can't hide it via TLP alone).
__global__ __launch_bounds__(256) void cov_kernel(const float* __restrict__ x,
                                                  double* __restrict__ gram,
                                                  double* __restrict__ chsum)
{
  __shared__ __align__(16) float tile[32][64];
  const int b   = blockIdx.x >> 5;
  const int ch  = blockIdx.x & 31;
  const int tid = threadIdx.x;
  const int ti = tid >> 4, tj = tid & 15;
  const int lrow = tid >> 4, lf4 = tid & 15;
  const int cch = tid & 63, crr = tid >> 6;
  float acc[4][4];
  #pragma unroll
  for (int a = 0; a < 4; ++a)
    #pragma unroll
    for (int c = 0; c < 4; ++c) acc[a][c] = 0.f;
  float csum = 0.f;
  const float* xb = x + ((size_t)b*65536 + (size_t)ch*2048)*64;
  float4 v0 = *(const float4*)(xb + (size_t)(lrow     )*64 + lf4*4);
  float4 v1 = *(const float4*)(xb + (size_t)(lrow + 16)*64 + lf4*4);
  for (int r0 = 0; r0 < 2048; r0 += 32){
    __syncthreads();
    *(float4*)&tile[lrow][lf4*4]      = v0;
    *(float4*)&tile[16 + lrow][lf4*4] = v1;
    __syncthreads();
    if (r0 + 32 < 2048){
      v0 = *(const float4*)(xb + (size_t)(r0 + 32 + lrow)*64 + lf4*4);
      v1 = *(const float4*)(xb + (size_t)(r0 + 48 + lrow)*64 + lf4*4);
    }
    #pragma unroll
    for (int rr = 0; rr < 32; ++rr){
      float4 xi = *(const float4*)&tile[rr][4*ti];
      float4 xj = *(const float4*)&tile[rr][4*tj];
      acc[0][0] += xi.x*xj.x; acc[0][1] += xi.x*xj.y; acc[0][2] += xi.x*xj.z; acc[0][3] += xi.x*xj.w;
      acc[1][0] += xi.y*xj.x; acc[1][1] += xi.y*xj.y; acc[1][2] += xi.y*xj.z; acc[1][3] += xi.y*xj.w;
      acc[2][0] += xi.z*xj.x; acc[2][1] += xi.z*xj.y; acc[2][2] += xi.z*xj.z; acc[2][3] += xi.z*xj.w;
      acc[3][0] += xi.w*xj.x; acc[3][1] += xi.w*xj.y; acc[3][2] += xi.w*xj.z; acc[3][3] += xi.w*xj.w;
    }
    #pragma unroll
    for (int rr2 = 0; rr2 < 8; ++rr2) csum += tile[crr + rr2*4][cch];
  }
  double* gb = gram + (size_t)b*4096;
  #pragma unroll
  for (int a = 0; a < 4; ++a)
    #pragma unroll
    for (int c = 0; c < 4; ++c)
      atomicAdd(&gb[(4*ti+a)*64 + (4*tj+c)], (double)acc[a][c]);
  atomicAdd(&chsum[b*64 + cch], (double)csum);
}

// ---------------- Phase B1: ssytd2, 256 threads (4-wave column split) ----------------
// Wave w owns columns 16w..16w+15. row = tid&63: every wave holds all 64 rows, so
// xn2/dot reductions run redundantly per-wave (identical inputs+order -> identical
// results -> uniform branches). Cross-wave combine only for the A.v partials.
__global__ __launch_bounds__(256) void tridiag_kernel(const double* __restrict__ gram,
                                                      const double* __restrict__ chsum,
                                                      double* __restrict__ dG,
                                                      double* __restrict__ eG,
                                                      double* __restrict__ tauG,
                                                      double* __restrict__ VlG,
                                                      float* __restrict__ meanG)
{
  __shared__ double As[64*65];
  __shared__ double vv_[64], wv_[64], mu_s[64], es_s[64], tau_s[64];
  __shared__ double part_s[4*64];     // [wave][row] — 2-lane/bank, conflict-free
  const int b = blockIdx.x;
  const int tid = threadIdx.x;
  const int row = tid & 63;
  const int wpart = tid >> 6;         // wave index == column-quarter index
  const int cbase = wpart * 16;
  const double* gb = gram + (size_t)b*4096;

  double mval = chsum[b*64+row]*(1.0/65536.0);
  if (tid < 64){
    meanG[b*64+row] = (float)mval;
    mu_s[row] = mval;
  }
  __syncthreads();
  for (int idx = tid; idx < 4096; idx += 256){
    int i = idx >> 6, j = idx & 63;
    As[i*65+j] = (gb[idx] - 65536.0*mu_s[i]*mu_s[j])*(1.0/65535.0);
  }
  __syncthreads();

  for (int i = 0; i < 63; ++i){
    double alpha = As[(i+1)*65+i];                       // uniform broadcast read
    double xv0 = (row >= i+2) ? As[row*65+i] : 0.0;
    double xn2 = wave_sum(xv0*xv0);                      // per-wave redundant
    if (xn2 == 0.0){
      if (tid < 64){
        es_s[i] = alpha; tau_s[i] = 0.0;
        VlG[((size_t)b*63 + i)*64 + row] = 0.0;
      }
      __syncthreads();
      continue;
    }
    double xnorm = sqrt(xn2);
    double betav = -fsign(slapy2(alpha, xnorm), alpha);
    double taui  = (betav-alpha)/betav;
    double invs  = 1.0/(alpha-betav);
    double vval = (row == i+1) ? 1.0 : ((row >= i+2) ? xv0*invs : 0.0);
    if (tid < 64){
      vv_[row] = vval;
      VlG[((size_t)b*63 + i)*64 + row] = vval;           // coalesced reflector store
    }
    __syncthreads();
    // A.v partial over this wave's 16 columns (consecutive -> b128 vectorizable;
    // vv_[c]=0 for c<=i so full range is exact)
    {
      double p0 = 0.0, p1 = 0.0, p2 = 0.0, p3 = 0.0;
      #pragma unroll
      for (int k = 0; k < 16; k += 4){
        p0 += As[row*65+cbase+k+0]*vv_[cbase+k+0];
        p1 += As[row*65+cbase+k+1]*vv_[cbase+k+1];
        p2 += As[row*65+cbase+k+2]*vv_[cbase+k+2];
        p3 += As[row*65+cbase+k+3]*vv_[cbase+k+3];
      }
      part_s[wpart*64 + row] = (p0+p1)+(p2+p3);
    }
    __syncthreads();
    double xvr = (part_s[row] + part_s[64+row]) + (part_s[128+row] + part_s[192+row]);
    xvr = (row >= i+1) ? xvr*taui : 0.0;
    double dot = wave_sum((row >= i+1) ? xvr*vval : 0.0); // per-wave redundant (identical)
    double alf = -0.5*taui*dot;
    double wvv = (row >= i+1) ? (xvr + alf*vval) : 0.0;
    if (tid < 64) wv_[row] = wvv;
    __syncthreads();
    // rank-2 update of this wave's 16 columns (wv_/vv_ zero outside active range)
    {
      double vr = vval, wr = wvv;
      #pragma unroll
      for (int k = 0; k < 16; ++k){
        int c = cbase + k;
        As[row*65+c] -= vr*wv_[c] + wr*vv_[c];
      }
    }
    if (tid < 64){ es_s[i] = betav; tau_s[i] = taui; }
    __syncthreads();
  }
  if (tid < 64){
    dG[b*64+row]   = As[row*65+row];
    eG[b*64+row]   = (row < 63) ? es_s[row]  : 0.0;
    tauG[b*64+row] = (row < 63) ? tau_s[row] : 0.0;
  }
}

// ---------------- Phase B2: 64 independent 16x16 steqr ----------------
__global__ __launch_bounds__(64) void steqr_kernel(double* __restrict__ dG,
                                                   const double* __restrict__ eG,
                                                   double* __restrict__ Zg)
{
  __shared__ double Zt[16*17];
  __shared__ double dd[16], ee[16], wc[20], wsn[20];
  const int b = blockIdx.x >> 2, s = blockIdx.x & 3;
  const int tid = threadIdx.x;

  // load tridiag segment + D&C rank-one cut adjustments
  {
    double dv = (tid < 16) ? dG[b*64 + 16*s + tid] : 0.0;
    if (tid == 0  && s > 0) dv -= fabs(eG[b*64 + 16*s - 1]);
    if (tid == 15 && s < 3) dv -= fabs(eG[b*64 + 16*s + 15]);
    if (tid < 16) dd[tid] = dv;
    if (tid < 15) ee[tid] = eG[b*64 + 16*s + tid];
    if (tid == 15) ee[15] = 0.0;
  }
  for (int idx = tid; idx < 16*17; idx += 64) Zt[idx] = 0.0;
  __syncthreads();
  if (tid < 16) Zt[tid*17+tid] = 1.0;
  __syncthreads();

  steqr16<17>(dd, ee, Zt, tid, wc, wsn);
  __syncthreads();

  // store compact 16x16 block + updated d
  for (int idx = tid; idx < 256; idx += 64){
    int r = idx >> 4, c = idx & 15;
    Zg[(size_t)b*4096 + s*256 + idx] = Zt[r*17+c];
  }
  if (tid < 16) dG[b*64 + 16*s + tid] = dd[tid];
}

// ---------------- Phase B3: two independent 16+16 merges (256 thr) ----------------
__global__ __launch_bounds__(256) void merge16_kernel(double* __restrict__ Zg,
                                                      double* __restrict__ dG,
                                                      const double* __restrict__ eG)
{
  __shared__ double Z32[32*33];
  __shared__ double dloc[32];
  __shared__ double zz[32], dl[32], ww[32], mu[32], wt[32];
  __shared__ int idxm[32], sv[32], tl[32], fp[32];
  const int b = blockIdx.x >> 1, h = blockIdx.x & 1;
  const int tid = threadIdx.x;

  for (int idx = tid; idx < 32*33; idx += 256) Z32[idx] = 0.0;
  if (tid < 32) dloc[tid] = dG[b*64 + 32*h + tid];
  __syncthreads();
  {
    int idx = tid;  // exactly 256 elements per 16x16 block
    int r = idx >> 4, c = idx & 15;
    Z32[r*33 + c]           = Zg[(size_t)b*4096 + (2*h)*256   + idx];
    Z32[(16+r)*33 + (16+c)] = Zg[(size_t)b*4096 + (2*h+1)*256 + idx];
  }
  __syncthreads();

  double rho_in = eG[b*64 + 32*h + 15];
  merge_dc<16,33>(Z32, dloc, rho_in, tid, zz, dl, ww, mu, wt, idxm, sv, tl, fp);

  // store 32x32 result to the upper half of Zg[b] (disjoint from the inputs)
  for (int idx = tid; idx < 1024; idx += 256){
    int r = idx >> 5, c = idx & 31;
    Zg[(size_t)b*4096 + 2048 + h*1024 + idx] = Z32[r*33 + c];
  }
  if (tid < 32) dG[b*64 + 32*h + tid] = dloc[tid];
}

// ---------------- Phase B4: 32+32 merge + back-transform + output V (256 thr) ----------------
__global__ __launch_bounds__(256) void merge32_bt_kernel(const double* __restrict__ Zg,
                                                         double* __restrict__ dG,
                                                         const double* __restrict__ eG,
                                                         const double* __restrict__ tauG,
                                                         const double* __restrict__ VlG,
                                                         float* __restrict__ Vt)
{
  __shared__ double Z64[64*65];
  __shared__ double Vl_s[63*64];
  __shared__ double dloc[64], tau_l[64];
  __shared__ double zz[64], dl[64], ww[64], mu[64], wt[64];
  __shared__ int idxm[64], sv[64], tl[64], fp[64];
  const int b = blockIdx.x;
  const int tid = threadIdx.x;

  for (int idx = tid; idx < 64*65; idx += 256) Z64[idx] = 0.0;
  if (tid < 64){ dloc[tid] = dG[b*64 + tid]; tau_l[tid] = tauG[b*64 + tid]; }
  // stage all reflectors once (kills per-step uniform global-load latency chains)
  for (int idx = tid; idx < 63*64; idx += 256) Vl_s[idx] = VlG[(size_t)b*63*64 + idx];
  __syncthreads();
  for (int idx = tid; idx < 1024; idx += 256){
    int r = idx >> 5, c = idx & 31;
    Z64[r*65 + c]           = Zg[(size_t)b*4096 + 2048 + idx];
    Z64[(32+r)*65 + (32+c)] = Zg[(size_t)b*4096 + 3072 + idx];
  }
  __syncthreads();

  double rho_in = eG[b*64 + 31];
  merge_dc<32,65>(Z64, dloc, rho_in, tid, zz, dl, ww, mu, wt, idxm, sv, tl, fp);

  // back-transform: Z := H1...H63 * Z, entirely in registers.
  // Lane (jc = tid>>2, part = tid&3) owns rows {part+4*rr} of column jc.
  // Vl rows are zero for r <= i and 1 at r == i+1, so the unguarded FMA form
  // reproduces the original guarded loops exactly.
  {
    const int jc = tid >> 2, part = tid & 3;
    double z[16];
    #pragma unroll
    for (int rr = 0; rr < 16; ++rr) z[rr] = Z64[(part + 4*rr)*65 + jc];
    for (int i = 62; i >= 0; --i){
      double taui = tau_l[i];
      if (taui == 0.0) continue;
      double vir[16];
      #pragma unroll
      for (int rr = 0; rr < 16; ++rr) vir[rr] = Vl_s[i*64 + part + 4*rr];
      double w0 = 0.0, w1 = 0.0;
      #pragma unroll
      for (int rr = 0; rr < 16; rr += 2){ w0 += vir[rr]*z[rr]; w1 += vir[rr+1]*z[rr+1]; }
      double w = w0 + w1;
      w += __shfl_xor(w, 1);
      w += __shfl_xor(w, 2);
      w *= taui;
      #pragma unroll
      for (int rr = 0; rr < 16; ++rr) z[rr] -= vir[rr]*w;
    }
    // each lane reads/writes only its own (row,col) elements -> no barrier needed
    #pragma unroll
    for (int rr = 0; rr < 16; ++rr) Z64[(part + 4*rr)*65 + jc] = z[rr];
  }
  __syncthreads();

  // Vt[b][c][k] = V[c][63-k]  (descending top-32)
  for (int idx = tid; idx < 2048; idx += 256){
    int c2 = idx >> 5, k = idx & 31;
    Vt[(size_t)b*2048 + idx] = (float)Z64[c2*65 + (63-k)];
  }
}

// ---------------- Phase C: projection ----------------
// R5: Vs read as float4 (b128 broadcast) — 512 LDS reads/thread instead of 2048.
__global__ __launch_bounds__(256) void proj_kernel(const float* __restrict__ x,
                                                   const float* __restrict__ Vt,
                                                   const float* __restrict__ meanf,
                                                   float* __restrict__ out)
{
  __shared__ __align__(16) float Vs[64][32];
  __shared__ float ms[64];
  const int b = blockIdx.x >> 8;
  const int rb = blockIdx.x & 255;
  const int tid = threadIdx.x;
  for (int idx = tid; idx < 2048; idx += 256) ((float*)Vs)[idx] = Vt[(size_t)b*2048 + idx];
  if (tid < 64) ms[tid] = meanf[b*64+tid];
  __syncthreads();
  const size_t row = (size_t)b*65536 + (size_t)rb*256 + tid;
  const float4* xr = (const float4*)(x + row*64);
  float acc[32];
  #pragma unroll
  for (int k = 0; k < 32; ++k) acc[k] = 0.f;
  #pragma unroll
  for (int c4 = 0; c4 < 16; ++c4){
    float4 xv = xr[c4];
    float t0 = xv.x - ms[4*c4+0];
    float t1 = xv.y - ms[4*c4+1];
    float t2 = xv.z - ms[4*c4+2];
    float t3 = xv.w - ms[4*c4+3];
    #pragma unroll
    for (int k4 = 0; k4 < 8; ++k4){
      const float4 a0 = *(const float4*)&Vs[4*c4+0][4*k4];
      const float4 a1 = *(const float4*)&Vs[4*c4+1][4*k4];
      const float4 a2 = *(const float4*)&Vs[4*c4+2][4*k4];
      const float4 a3 = *(const float4*)&Vs[4*c4+3][4*k4];
      acc[4*k4+0] += t0*a0.x + t1*a1.x + t2*a2.x + t3*a3.x;
      acc[4*k4+1] += t0*a0.y + t1*a1.y + t2*a2.y + t3*a3.y;
      acc[4*k4+2] += t0*a0.z + t1*a1.z + t2*a2.z + t3*a3.z;
      acc[4*k4+3] += t0*a0.w + t1*a1.w + t2*a2.w + t3*a3.w;
    }
  }
  float4* op = (float4*)(out + row*32);
  #pragma unroll
  for (int k4 = 0; k4 < 8; ++k4)
    op[k4] = make_float4(acc[4*k4], acc[4*k4+1], acc[4*k4+2], acc[4*k4+3]);
}

extern "C" void kernel_launch(void* const* d_in, const int* in_sizes, int n_in,
                              void* d_out, int out_size, void* d_ws, size_t ws_size,
                              hipStream_t stream)
{
  const float* x = (const float*)d_in[0];
  float* out = (float*)d_out;
  char* ws = (char*)d_ws;
  // ws layout (bytes):
  //   [0,       524288) gram 16x64x64 dbl (atomics; zeroed) -> reused as Zg after tridiag
  //   [524288,  532480) chsum 16x64 dbl (atomics; zeroed)
  //   [532480,  540672) dG   16x64 dbl
  //   [540672,  548864) eG   16x64 dbl
  //   [548864,  557056) tauG 16x64 dbl
  //   [557056, 1073152) VlG  16x63x64 dbl (reflectors, transposed: Vl[b][i][r])
  //   [1073152,1204224) Vt   16x64x32 f32
  //   [1204224,1208320) mean 16x64 f32
  double* gram  = (double*)(ws);
  double* Zg    = (double*)(ws);             // alias: gram dead after tridiag_kernel
  double* chsum = (double*)(ws + 524288);
  double* dG    = (double*)(ws + 532480);
  double* eG    = (double*)(ws + 540672);
  double* tauG  = (double*)(ws + 548864);
  double* VlG   = (double*)(ws + 557056);
  float*  Vt    = (float*) (ws + 1073152);
  float*  mf    = (float*) (ws + 1204224);

  hipMemsetAsync(ws, 0, 532480, stream);
  cov_kernel     <<<dim3(512),  dim3(256), 0, stream>>>(x, gram, chsum);
  tridiag_kernel <<<dim3(16),   dim3(256), 0, stream>>>(gram, chsum, dG, eG, tauG, VlG, mf);
  steqr_kernel   <<<dim3(64),   dim3(64),  0, stream>>>(dG, eG, Zg);
  merge16_kernel <<<dim3(32),   dim3(256), 0, stream>>>(Zg, dG, eG);
  merge32_bt_kernel<<<dim3(16), dim3(256), 0, stream>>>(Zg, dG, eG, tauG, VlG, Vt);
  proj_kernel    <<<dim3(4096), dim3(256), 0, stream>>>(x, Vt, mf, out);
}